// Round 10
// baseline (200.352 us; speedup 1.0000x reference)
//
#include <hip/hip_runtime.h>

typedef __bf16 bf16x8 __attribute__((ext_vector_type(8)));
typedef float f32x4 __attribute__((ext_vector_type(4)));
typedef float fl4 __attribute__((ext_vector_type(4)));
typedef unsigned short us4 __attribute__((ext_vector_type(4)));
typedef unsigned short us8 __attribute__((ext_vector_type(8)));

__device__ __forceinline__ unsigned short f2bf(float f) {
  unsigned u = __builtin_bit_cast(unsigned, f);
  u += 0x7fffu + ((u >> 16) & 1u);
  return (unsigned short)(u >> 16);
}
__device__ __forceinline__ float bf2f(unsigned short h) {
  unsigned u = ((unsigned)h) << 16;
  return __builtin_bit_cast(float, u);
}

__device__ __forceinline__ void async16(const void* g, void* l) {
  __builtin_amdgcn_global_load_lds(
      (const __attribute__((address_space(1))) unsigned int*)g,
      (__attribute__((address_space(3))) unsigned int*)l, 16, 0, 0);
}

#define BARM() asm volatile("s_barrier" ::: "memory")
#define VMCNT4() asm volatile("s_waitcnt vmcnt(4)" ::: "memory")
#define VMCNT6() asm volatile("s_waitcnt vmcnt(6)" ::: "memory")
#define LGKM0() asm volatile("s_waitcnt lgkmcnt(0)" ::: "memory")
#define LGKM8() asm volatile("s_waitcnt lgkmcnt(8)" ::: "memory")
#define SCHEDB() __builtin_amdgcn_sched_barrier(0)

// ---------------- fp32 -> bf16 convert (x and W merged) ----------------
__global__ __launch_bounds__(256) void cvt_bf16_2(const float* __restrict__ sA,
                                                  unsigned short* __restrict__ dA, int nA,
                                                  const float* __restrict__ sB,
                                                  unsigned short* __restrict__ dB, int nB) {
  int i = blockIdx.x * 256 + threadIdx.x;
  const float* s;
  unsigned short* d;
  if (i < nA) {
    s = sA; d = dA;
  } else {
    i -= nA;
    if (i >= nB) return;
    s = sB; d = dB;
  }
  fl4 f = ((const fl4*)s)[i];
  us4 o;
  o[0] = f2bf(f[0]); o[1] = f2bf(f[1]); o[2] = f2bf(f[2]); o[3] = f2bf(f[3]);
  ((us4*)d)[i] = o;
}

// ---------------- transpose v: vT[b][c][t] = kqv[b*2048+t][2048+c] ----------------
__global__ __launch_bounds__(256) void transpose_v(const unsigned short* __restrict__ kqv,
                                                   unsigned short* __restrict__ vT) {
  int b = blockIdx.z;
  int t0 = blockIdx.x * 64;
  int c0 = blockIdx.y * 64;
  __shared__ unsigned short tile[64][68];
  int tid = threadIdx.x;
#pragma unroll
  for (int i = 0; i < 4; ++i) {
    int idx = i * 256 + tid;
    int r = idx >> 4;
    int c4 = (idx & 15) * 4;
    const unsigned short* src = kqv + ((size_t)(b * 2048 + t0 + r)) * 3072 + 2048 + c0 + c4;
    us4 v = *(const us4*)src;
    *(us4*)&tile[r][c4] = v;
  }
  __syncthreads();
#pragma unroll
  for (int i = 0; i < 4; ++i) {
    int idx = i * 256 + tid;
    int rc = idx >> 4;
    int t4 = (idx & 15) * 4;
    us4 v;
    v[0] = tile[t4 + 0][rc]; v[1] = tile[t4 + 1][rc];
    v[2] = tile[t4 + 2][rc]; v[3] = tile[t4 + 3][rc];
    unsigned short* dst = vT + ((size_t)(b * 1024 + c0 + rc)) * 2048 + t0 + t4;
    *(us4*)dst = v;
  }
}

// ---------------- g0: 128x384 8-phase GEMM, 512 blocks = 2 exact rounds -------
__global__ __launch_bounds__(512, 2) void gemm_g0(
    const unsigned short* __restrict__ A, const unsigned short* __restrict__ B,
    unsigned short* __restrict__ C, const float* __restrict__ bias) {
  const int flat = blockIdx.x;
  const int swz = (flat & 7) * 64 + (flat >> 3);   // XCD-contiguous remap
  const int bx = swz & 7;
  const int by = swz >> 3;
  const int rowBase = by * 128, colBase = bx * 384;
  const int lda = 1024, ldc = 3072, nk = 16;

  __shared__ __align__(16) unsigned char lds[131072];
  const int tid = threadIdx.x;
  const int lane = tid & 63, wid = tid >> 6;
  const int wr = wid >> 2, wc = wid & 3;
  const int l15 = lane & 15, l4 = lane >> 4, l7 = lane & 7;

  f32x4 acc[4][6] = {};
  bf16x8 af01[2][2], af23[2][2], bf[6][2];

  const unsigned short* Ab = A + (size_t)rowBase * lda;
  const unsigned short* Bb = B + (size_t)colBase * lda;
  unsigned aoff[2], boff[6], aldso[2], bldso[6];
#pragma unroll
  for (int i = 0; i < 6; ++i) {
    int off = i * 8192 + tid * 16;
    int r = off >> 7;
    int sb = ((off >> 4) & 7) ^ (r & 7);
    if (i < 2) { aoff[i] = (unsigned)(r * lda + sb * 8); aldso[i] = (unsigned)off; }
    boff[i] = (unsigned)(r * lda + sb * 8);
    bldso[i] = (unsigned)off;
  }

  auto STA = [&](int bufc, int op, int koff) {
    async16(Ab + (size_t)(aoff[op] + (unsigned)koff), lds + bufc * 65536 + aldso[op]);
  };
  auto STB = [&](int bufc, int op, int koff) {
    async16(Bb + (size_t)(boff[op] + (unsigned)koff),
            lds + bufc * 65536 + 16384 + bldso[op]);
  };
  auto RA = [&](int bufc, int m, int kk) -> bf16x8 {
    int row = wr * 64 + m * 16 + l15;
    int blk = (kk * 4 + l4) ^ l7;
    return *(const bf16x8*)(lds + bufc * 65536 + row * 128 + blk * 16);
  };
  auto RB = [&](int bufc, int n, int kk) -> bf16x8 {
    int row = wc * 96 + n * 16 + l15;
    int blk = (kk * 4 + l4) ^ l7;
    return *(const bf16x8*)(lds + bufc * 65536 + 16384 + row * 128 + blk * 16);
  };

#define RD_A01(BUF)                                                            \
  _Pragma("unroll") for (int mi = 0; mi < 2; ++mi)                             \
  _Pragma("unroll") for (int kk = 0; kk < 2; ++kk) af01[mi][kk] = RA((BUF), mi, kk)
#define RD_A23(BUF)                                                            \
  _Pragma("unroll") for (int mi = 0; mi < 2; ++mi)                             \
  _Pragma("unroll") for (int kk = 0; kk < 2; ++kk) af23[mi][kk] = RA((BUF), 2 + mi, kk)
#define RD_B(BUF, N0)                                                          \
  _Pragma("unroll") for (int nj = 0; nj < 3; ++nj)                             \
  _Pragma("unroll") for (int kk = 0; kk < 2; ++kk) bf[(N0) + nj][kk] = RB((BUF), (N0) + nj, kk)

#define MQ(MB, NB, AF)                                                         \
  _Pragma("unroll") for (int kk = 0; kk < 2; ++kk)                             \
  _Pragma("unroll") for (int mi = 0; mi < 2; ++mi)                             \
  _Pragma("unroll") for (int nj = 0; nj < 3; ++nj)                             \
      acc[(MB) + mi][(NB) + nj] = __builtin_amdgcn_mfma_f32_16x16x32_bf16(     \
          AF[mi][kk], bf[(NB) + nj][kk], acc[(MB) + mi][(NB) + nj], 0, 0, 0)

#define PHASE(RDS, STG, GATE, MB, NB, AF)                                      \
  do {                                                                         \
    RDS;                                                                       \
    STG;                                                                       \
    BARM();                                                                    \
    LGKM0();                                                                   \
    SCHEDB();                                                                  \
    __builtin_amdgcn_s_setprio(1);                                             \
    MQ(MB, NB, AF);                                                            \
    __builtin_amdgcn_s_setprio(0);                                             \
    GATE;                                                                      \
    BARM();                                                                    \
  } while (0)

  STA(0, 0, 0); STA(0, 1, 0);
#pragma unroll
  for (int i = 0; i < 6; ++i) STB(0, i, 0);
#pragma unroll
  for (int i = 0; i < 6; ++i) STB(1, i, 64);
  VMCNT6();
  BARM();

  for (int it = 0; it < 8; ++it) {
    int t = it * 2;
    int kA1 = (t + 1) * 64;
    int k2 = (t + 2 < nk - 1 ? t + 2 : nk - 1) * 64;
    int k3 = (t + 3 < nk - 1 ? t + 3 : nk - 1) * 64;
    PHASE({ RD_A01(0); RD_B(0, 0); }, { STA(1, 0, kA1); STA(1, 1, kA1); },
          (void)0, 0, 0, af01);
    PHASE({ RD_A23(0); RD_B(0, 3); }, (void)0, (void)0, 0, 3, af01);
    PHASE({}, { STB(0, 0, k2); STB(0, 1, k2); STB(0, 2, k2); },
          (void)0, 2, 3, af23);
    PHASE({}, { STB(0, 3, k2); STB(0, 4, k2); STB(0, 5, k2); },
          VMCNT6(), 2, 0, af23);
    PHASE({ RD_A01(1); RD_B(1, 0); }, { STA(0, 0, k2); STA(0, 1, k2); },
          (void)0, 0, 0, af01);
    PHASE({ RD_A23(1); RD_B(1, 3); }, (void)0, (void)0, 0, 3, af01);
    PHASE({}, { STB(1, 0, k3); STB(1, 1, k3); STB(1, 2, k3); },
          (void)0, 2, 3, af23);
    PHASE({}, { STB(1, 3, k3); STB(1, 4, k3); STB(1, 5, k3); },
          VMCNT6(), 2, 0, af23);
  }
#undef PHASE
#undef MQ
#undef RD_A01
#undef RD_A23
#undef RD_B

  const int cr = l4 * 4;
#pragma unroll
  for (int n = 0; n < 6; ++n) {
    int col = colBase + wc * 96 + n * 16 + l15;
    float bv = bias[col];
#pragma unroll
    for (int m = 0; m < 4; ++m) {
      int row = rowBase + wr * 64 + m * 16 + cr;
#pragma unroll
      for (int i = 0; i < 4; ++i)
        C[(size_t)(row + i) * ldc + col] = f2bf(acc[m][n][i] + bv);
    }
  }
}

// ---------------- 256x256 8-phase bf16 MFMA GEMM (g1, and g2 split-K2) --------
// EPI 1: bf16 out * scale, skip blocks above diagonal.
// EPI 2: split-K2 causal PV: y -> (by = 7 - y/2 heavy-first, h = y&1); each half
// computes 2(by+1) K-tiles and unsafeAtomicAdd's f32 partials onto zeroed out.
template <int EPI>
__global__ __launch_bounds__(512, 2) void gemm8p(
    const unsigned short* __restrict__ A, int lda, long long sA,
    const unsigned short* __restrict__ B, int ldb, long long sB,
    void* __restrict__ Cv, int ldc, long long sC,
    float scale, int K) {
  int bx = blockIdx.x, by = blockIdx.y, h = 0;
  const int bz = blockIdx.z;
  if (EPI == 1 && bx > by) return;
  if (EPI == 2) { by = 7 - (blockIdx.y >> 1); h = blockIdx.y & 1; }
  A += (size_t)bz * sA;
  B += (size_t)bz * sB;
  const int rowBase = by * 256;
  const int colBase = bx * 256;
  int kt0, nkh;
  if (EPI == 2) {
    int nk = (rowBase + 256) / 64;   // 4(by+1), even
    nkh = nk >> 1;                   // 2(by+1)
    kt0 = h * nkh;
  } else {
    kt0 = 0; nkh = K / 64;
  }
  const int ktEnd = kt0 + nkh - 1;

  __shared__ __align__(16) unsigned char lds[131072];
  const int tid = threadIdx.x;
  const int lane = tid & 63;
  const int wid = tid >> 6;
  const int wr = wid >> 2;
  const int wc = wid & 3;
  const int l15 = lane & 15, l4 = lane >> 4, l7 = lane & 7;

  f32x4 acc[8][4] = {};
  bf16x8 af0[4][2], af1[4][2], bf0[2][2], bf1[2][2];

  const unsigned short* Ab = A + (size_t)rowBase * lda;
  const unsigned short* Bb = B + (size_t)colBase * ldb;
  unsigned loff[2][2];
  unsigned lldso[2];
#pragma unroll
  for (int i = 0; i < 2; ++i) {
    int off = (i * 512 + tid) * 16;
    int r = off >> 7;
    int sb = ((off >> 4) & 7) ^ (r & 7);
    lldso[i] = (unsigned)off;
#pragma unroll
    for (int hh = 0; hh < 2; ++hh)
      loff[hh][i] = (unsigned)((hh * 128 + r) * lda + sb * 8);
  }

  auto STAGE = [&](int bufc, int isB, int half, const unsigned short* Gb, int koff) {
#pragma unroll
    for (int i = 0; i < 2; ++i)
      async16(Gb + (size_t)(loff[half][i] + (unsigned)koff),
              lds + bufc * 65536 + isB * 32768 + half * 16384 + lldso[i]);
  };
  auto RDA = [&](int bufc, int m, int kk) -> bf16x8 {
    int row = m * 16 + l15;
    int blk = (kk * 4 + l4) ^ l7;
    return *(const bf16x8*)(lds + bufc * 65536 + wr * 16384 + row * 128 + blk * 16);
  };
  auto RDB = [&](int bufc, int n, int kk) -> bf16x8 {
    int row = (wc & 1) * 64 + n * 16 + l15;
    int blk = (kk * 4 + l4) ^ l7;
    return *(const bf16x8*)(lds + bufc * 65536 + 32768 + (wc >> 1) * 16384 +
                            row * 128 + blk * 16);
  };

#define RDA8(dst, BUF, Q)                                                      \
  _Pragma("unroll") for (int mi = 0; mi < 4; ++mi)                             \
  _Pragma("unroll") for (int kk = 0; kk < 2; ++kk)                             \
      dst[mi][kk] = RDA((BUF), (Q) * 4 + mi, kk)
#define RDB4(dst, BUF, NB)                                                     \
  _Pragma("unroll") for (int nj = 0; nj < 2; ++nj)                             \
  _Pragma("unroll") for (int kk = 0; kk < 2; ++kk)                             \
      dst[nj][kk] = RDB((BUF), (NB) + nj, kk)

#define MFMAQ(MB, NB, AF, BF)                                                  \
  _Pragma("unroll") for (int kk = 0; kk < 2; ++kk)                             \
  _Pragma("unroll") for (int mi = 0; mi < 4; ++mi)                             \
  _Pragma("unroll") for (int nj = 0; nj < 2; ++nj)                             \
      acc[(MB) + mi][(NB) + nj] = __builtin_amdgcn_mfma_f32_16x16x32_bf16(     \
          AF[mi][kk], BF[nj][kk], acc[(MB) + mi][(NB) + nj], 0, 0, 0)

#define PH(RDS, STG, HINT, GATE, MB, NB, AF, BF)                               \
  do {                                                                         \
    RDS;                                                                       \
    STG;                                                                       \
    HINT;                                                                      \
    BARM();                                                                    \
    LGKM0();                                                                   \
    SCHEDB();                                                                  \
    __builtin_amdgcn_s_setprio(1);                                             \
    MFMAQ(MB, NB, AF, BF);                                                     \
    __builtin_amdgcn_s_setprio(0);                                             \
    GATE;                                                                      \
    BARM();                                                                    \
  } while (0)

  STAGE(0, 0, 0, Ab, kt0 * 64);
  STAGE(0, 0, 1, Ab, kt0 * 64);
  STAGE(0, 1, 0, Bb, kt0 * 64);
  STAGE(0, 1, 1, Bb, kt0 * 64);
  {
    int k1 = ((kt0 + 1 < ktEnd) ? kt0 + 1 : ktEnd) * 64;
    STAGE(1, 1, 0, Bb, k1);
    STAGE(1, 1, 1, Bb, k1);
  }
  VMCNT4();
  BARM();

  const int nt2 = nkh >> 1;
  for (int it = 0; it < nt2; ++it) {
    int t = kt0 + it * 2;
    int kA1 = (t + 1) * 64;
    int k2 = (t + 2 < ktEnd ? t + 2 : ktEnd) * 64;
    int k3 = (t + 3 < ktEnd ? t + 3 : ktEnd) * 64;
    PH({ RDA8(af0, 0, 0); RDB4(bf0, 0, 0); }, STAGE(1, 0, 0, Ab, kA1), LGKM8(),
       (void)0, 0, 0, af0, bf0);
    PH({ RDB4(bf1, 0, 2); }, STAGE(1, 0, 1, Ab, kA1), (void)0,
       (void)0, 0, 2, af0, bf1);
    PH({ RDA8(af1, 0, 1); }, STAGE(0, 1, 0, Bb, k2), (void)0,
       (void)0, 4, 2, af1, bf1);
    PH({}, STAGE(0, 1, 1, Bb, k2), (void)0,
       VMCNT4(), 4, 0, af1, bf0);
    PH({ RDA8(af0, 1, 0); RDB4(bf0, 1, 0); }, STAGE(0, 0, 0, Ab, k2), LGKM8(),
       (void)0, 0, 0, af0, bf0);
    PH({ RDB4(bf1, 1, 2); }, STAGE(0, 0, 1, Ab, k2), (void)0,
       (void)0, 0, 2, af0, bf1);
    PH({ RDA8(af1, 1, 1); }, STAGE(1, 1, 0, Bb, k3), (void)0,
       (void)0, 4, 2, af1, bf1);
    PH({}, STAGE(1, 1, 1, Bb, k3), (void)0,
       VMCNT4(), 4, 0, af1, bf0);
  }
#undef PH
#undef MFMAQ
#undef RDA8
#undef RDB4

  const int cr = l4 * 4;
  if constexpr (EPI == 1) {
    unsigned short* C = (unsigned short*)Cv + (size_t)bz * sC;
#pragma unroll
    for (int n = 0; n < 4; ++n) {
      int col = colBase + wc * 64 + n * 16 + l15;
#pragma unroll
      for (int m = 0; m < 8; ++m) {
        int row = rowBase + wr * 128 + m * 16 + cr;
#pragma unroll
        for (int i = 0; i < 4; ++i)
          C[(size_t)(row + i) * ldc + col] = f2bf(acc[m][n][i] * scale);
      }
    }
  } else {
    float* C = (float*)Cv + (size_t)bz * sC;
#pragma unroll
    for (int n = 0; n < 4; ++n) {
      int col = colBase + wc * 64 + n * 16 + l15;
#pragma unroll
      for (int m = 0; m < 8; ++m) {
        int row = rowBase + wr * 128 + m * 16 + cr;
#pragma unroll
        for (int i = 0; i < 4; ++i)
          unsafeAtomicAdd(&C[(size_t)(row + i) * ldc + col], acc[m][n][i]);
      }
    }
  }
}

// ---------------- causal softmax over S rows (in place, bf16) ----------------
__global__ __launch_bounds__(256) void softmax_causal(unsigned short* __restrict__ S) {
  const int T = 2048;
  int t = blockIdx.x, b = blockIdx.y;
  unsigned short* row = S + ((size_t)b * T + t) * T;
  const int nv = t + 1;
  const int bound = ((t >> 8) + 1) << 8;
  int tid = threadIdx.x;
  int lane = tid & 63, wid = tid >> 6;
  int s0 = tid * 8;
  us8 raw = {};
  if (s0 < nv) raw = *(const us8*)(row + s0);
  float v[8];
  float m = -3.0e38f;
#pragma unroll
  for (int j = 0; j < 8; ++j) {
    v[j] = bf2f(raw[j]);
    if (s0 + j < nv) m = fmaxf(m, v[j]);
  }
#pragma unroll
  for (int o = 32; o > 0; o >>= 1) m = fmaxf(m, __shfl_xor(m, o, 64));
  __shared__ float red[4];
  if (lane == 0) red[wid] = m;
  __syncthreads();
  m = fmaxf(fmaxf(red[0], red[1]), fmaxf(red[2], red[3]));
  __syncthreads();
  float sum = 0.f;
#pragma unroll
  for (int j = 0; j < 8; ++j) {
    float e = (s0 + j < nv) ? exp2f(v[j] - m) : 0.f;
    v[j] = e;
    sum += e;
  }
#pragma unroll
  for (int o = 32; o > 0; o >>= 1) sum += __shfl_xor(sum, o, 64);
  if (lane == 0) red[wid] = sum;
  __syncthreads();
  sum = red[0] + red[1] + red[2] + red[3];
  float inv = 1.0f / sum;
  if (s0 < bound) {
    us8 outv;
#pragma unroll
    for (int j = 0; j < 8; ++j) outv[j] = f2bf(v[j] * inv);
    *(us8*)(row + s0) = outv;
  }
}

extern "C" void kernel_launch(void* const* d_in, const int* in_sizes, int n_in,
                              void* d_out, int out_size, void* d_ws, size_t ws_size,
                              hipStream_t stream) {
  const float* x = (const float*)d_in[0];      // [4,2048,1024]
  const float* W = (const float*)d_in[1];      // [3072,1024]
  const float* bias = (const float*)d_in[2];   // [3072]
  float* out = (float*)d_out;                  // [4,2048,1024]

  char* ws = (char*)d_ws;
  if (ws_size < 106954752u) return;
  unsigned short* xbf = (unsigned short*)(ws);
  unsigned short* vT = xbf;  // alias: xbf dead after gemm_g0
  unsigned short* wbf = (unsigned short*)(ws + 16777216);
  unsigned short* kqv = (unsigned short*)(ws + 23068672);
  unsigned short* S = (unsigned short*)(ws + 73400320);

  const float kSoftmaxScale = 1.4426950408889634f / 32.0f;  // log2(e)/sqrt(1024)

  // zero out for split-K atomic accumulation (graph-capture-safe)
  hipMemsetAsync(out, 0, (size_t)out_size * 4, stream);

  cvt_bf16_2<<<11264, 256, 0, stream>>>(x, xbf, 2097152, W, wbf, 786432);

  // kqv = x @ W^T + b : 128x384 tiles, 8x64 = 512 blocks = 2 exact rounds
  gemm_g0<<<dim3(512, 1, 1), 512, 0, stream>>>(xbf, wbf, kqv, bias);

  transpose_v<<<dim3(32, 16, 4), 256, 0, stream>>>(kqv, vT);

  // S = (k @ q^T) * log2e/32 (bf16), causal blocks skipped
  gemm8p<1><<<dim3(8, 8, 4), 512, 0, stream>>>(
      kqv, 3072, 2048LL * 3072, kqv + 1024, 3072, 2048LL * 3072,
      S, 2048, 2048LL * 2048, kSoftmaxScale, 1024);

  softmax_causal<<<dim3(2048, 4), 256, 0, stream>>>(S);

  // out += P @ vT^T (fp32), split-K2, heavy halves first, 256 blocks = 1/CU
  gemm8p<2><<<dim3(4, 16, 4), 512, 0, stream>>>(
      S, 2048, 2048LL * 2048, vT, 2048, 1024LL * 2048,
      out, 1024, 2048LL * 1024, 1.0f, 2048);
}

// Round 11
// 171.314 us; speedup vs baseline: 1.1695x; 1.1695x over previous
//
#include <hip/hip_runtime.h>

typedef __bf16 bf16x8 __attribute__((ext_vector_type(8)));
typedef float f32x4 __attribute__((ext_vector_type(4)));
typedef float fl4 __attribute__((ext_vector_type(4)));
typedef unsigned short us4 __attribute__((ext_vector_type(4)));
typedef unsigned short us8 __attribute__((ext_vector_type(8)));

__device__ __forceinline__ unsigned short f2bf(float f) {
  unsigned u = __builtin_bit_cast(unsigned, f);
  u += 0x7fffu + ((u >> 16) & 1u);
  return (unsigned short)(u >> 16);
}
__device__ __forceinline__ float bf2f(unsigned short h) {
  unsigned u = ((unsigned)h) << 16;
  return __builtin_bit_cast(float, u);
}

__device__ __forceinline__ void async16(const void* g, void* l) {
  __builtin_amdgcn_global_load_lds(
      (const __attribute__((address_space(1))) unsigned int*)g,
      (__attribute__((address_space(3))) unsigned int*)l, 16, 0, 0);
}

#define BARM() asm volatile("s_barrier" ::: "memory")
#define VMCNT4() asm volatile("s_waitcnt vmcnt(4)" ::: "memory")
#define VMCNT6() asm volatile("s_waitcnt vmcnt(6)" ::: "memory")
#define LGKM0() asm volatile("s_waitcnt lgkmcnt(0)" ::: "memory")
#define LGKM8() asm volatile("s_waitcnt lgkmcnt(8)" ::: "memory")
#define SCHEDB() __builtin_amdgcn_sched_barrier(0)

// ---------------- fp32 -> bf16 convert (x and W merged) ----------------
__global__ __launch_bounds__(256) void cvt_bf16_2(const float* __restrict__ sA,
                                                  unsigned short* __restrict__ dA, int nA,
                                                  const float* __restrict__ sB,
                                                  unsigned short* __restrict__ dB, int nB) {
  int i = blockIdx.x * 256 + threadIdx.x;
  const float* s;
  unsigned short* d;
  if (i < nA) {
    s = sA; d = dA;
  } else {
    i -= nA;
    if (i >= nB) return;
    s = sB; d = dB;
  }
  fl4 f = ((const fl4*)s)[i];
  us4 o;
  o[0] = f2bf(f[0]); o[1] = f2bf(f[1]); o[2] = f2bf(f[2]); o[3] = f2bf(f[3]);
  ((us4*)d)[i] = o;
}

// ---------------- transpose v: vT[b][c][t] = kqv[b*2048+t][2048+c] ----------------
__global__ __launch_bounds__(256) void transpose_v(const unsigned short* __restrict__ kqv,
                                                   unsigned short* __restrict__ vT) {
  int b = blockIdx.z;
  int t0 = blockIdx.x * 64;
  int c0 = blockIdx.y * 64;
  __shared__ unsigned short tile[64][68];
  int tid = threadIdx.x;
#pragma unroll
  for (int i = 0; i < 4; ++i) {
    int idx = i * 256 + tid;
    int r = idx >> 4;
    int c4 = (idx & 15) * 4;
    const unsigned short* src = kqv + ((size_t)(b * 2048 + t0 + r)) * 3072 + 2048 + c0 + c4;
    us4 v = *(const us4*)src;
    *(us4*)&tile[r][c4] = v;
  }
  __syncthreads();
#pragma unroll
  for (int i = 0; i < 4; ++i) {
    int idx = i * 256 + tid;
    int rc = idx >> 4;
    int t4 = (idx & 15) * 4;
    us4 v;
    v[0] = tile[t4 + 0][rc]; v[1] = tile[t4 + 1][rc];
    v[2] = tile[t4 + 2][rc]; v[3] = tile[t4 + 3][rc];
    unsigned short* dst = vT + ((size_t)(b * 1024 + c0 + rc)) * 2048 + t0 + t4;
    *(us4*)dst = v;
  }
}

// ---------------- g0: 128x384 8-phase GEMM, 512 blocks = 2 exact rounds -------
__global__ __launch_bounds__(512, 2) void gemm_g0(
    const unsigned short* __restrict__ A, const unsigned short* __restrict__ B,
    unsigned short* __restrict__ C, const float* __restrict__ bias) {
  const int flat = blockIdx.x;
  const int swz = (flat & 7) * 64 + (flat >> 3);   // XCD-contiguous remap
  const int bx = swz & 7;
  const int by = swz >> 3;
  const int rowBase = by * 128, colBase = bx * 384;
  const int lda = 1024, ldc = 3072, nk = 16;

  __shared__ __align__(16) unsigned char lds[131072];
  const int tid = threadIdx.x;
  const int lane = tid & 63, wid = tid >> 6;
  const int wr = wid >> 2, wc = wid & 3;
  const int l15 = lane & 15, l4 = lane >> 4, l7 = lane & 7;

  f32x4 acc[4][6] = {};
  bf16x8 af01[2][2], af23[2][2], bf[6][2];

  const unsigned short* Ab = A + (size_t)rowBase * lda;
  const unsigned short* Bb = B + (size_t)colBase * lda;
  unsigned aoff[2], boff[6], aldso[2], bldso[6];
#pragma unroll
  for (int i = 0; i < 6; ++i) {
    int off = i * 8192 + tid * 16;
    int r = off >> 7;
    int sb = ((off >> 4) & 7) ^ (r & 7);
    if (i < 2) { aoff[i] = (unsigned)(r * lda + sb * 8); aldso[i] = (unsigned)off; }
    boff[i] = (unsigned)(r * lda + sb * 8);
    bldso[i] = (unsigned)off;
  }

  auto STA = [&](int bufc, int op, int koff) {
    async16(Ab + (size_t)(aoff[op] + (unsigned)koff), lds + bufc * 65536 + aldso[op]);
  };
  auto STB = [&](int bufc, int op, int koff) {
    async16(Bb + (size_t)(boff[op] + (unsigned)koff),
            lds + bufc * 65536 + 16384 + bldso[op]);
  };
  auto RA = [&](int bufc, int m, int kk) -> bf16x8 {
    int row = wr * 64 + m * 16 + l15;
    int blk = (kk * 4 + l4) ^ l7;
    return *(const bf16x8*)(lds + bufc * 65536 + row * 128 + blk * 16);
  };
  auto RB = [&](int bufc, int n, int kk) -> bf16x8 {
    int row = wc * 96 + n * 16 + l15;
    int blk = (kk * 4 + l4) ^ l7;
    return *(const bf16x8*)(lds + bufc * 65536 + 16384 + row * 128 + blk * 16);
  };

#define RD_A01(BUF)                                                            \
  _Pragma("unroll") for (int mi = 0; mi < 2; ++mi)                             \
  _Pragma("unroll") for (int kk = 0; kk < 2; ++kk) af01[mi][kk] = RA((BUF), mi, kk)
#define RD_A23(BUF)                                                            \
  _Pragma("unroll") for (int mi = 0; mi < 2; ++mi)                             \
  _Pragma("unroll") for (int kk = 0; kk < 2; ++kk) af23[mi][kk] = RA((BUF), 2 + mi, kk)
#define RD_B(BUF, N0)                                                          \
  _Pragma("unroll") for (int nj = 0; nj < 3; ++nj)                             \
  _Pragma("unroll") for (int kk = 0; kk < 2; ++kk) bf[(N0) + nj][kk] = RB((BUF), (N0) + nj, kk)

#define MQ(MB, NB, AF)                                                         \
  _Pragma("unroll") for (int kk = 0; kk < 2; ++kk)                             \
  _Pragma("unroll") for (int mi = 0; mi < 2; ++mi)                             \
  _Pragma("unroll") for (int nj = 0; nj < 3; ++nj)                             \
      acc[(MB) + mi][(NB) + nj] = __builtin_amdgcn_mfma_f32_16x16x32_bf16(     \
          AF[mi][kk], bf[(NB) + nj][kk], acc[(MB) + mi][(NB) + nj], 0, 0, 0)

#define PHASE(RDS, STG, GATE, MB, NB, AF)                                      \
  do {                                                                         \
    RDS;                                                                       \
    STG;                                                                       \
    BARM();                                                                    \
    LGKM0();                                                                   \
    SCHEDB();                                                                  \
    __builtin_amdgcn_s_setprio(1);                                             \
    MQ(MB, NB, AF);                                                            \
    __builtin_amdgcn_s_setprio(0);                                             \
    GATE;                                                                      \
    BARM();                                                                    \
  } while (0)

  STA(0, 0, 0); STA(0, 1, 0);
#pragma unroll
  for (int i = 0; i < 6; ++i) STB(0, i, 0);
#pragma unroll
  for (int i = 0; i < 6; ++i) STB(1, i, 64);
  VMCNT6();
  BARM();

  for (int it = 0; it < 8; ++it) {
    int t = it * 2;
    int kA1 = (t + 1) * 64;
    int k2 = (t + 2 < nk - 1 ? t + 2 : nk - 1) * 64;
    int k3 = (t + 3 < nk - 1 ? t + 3 : nk - 1) * 64;
    PHASE({ RD_A01(0); RD_B(0, 0); }, { STA(1, 0, kA1); STA(1, 1, kA1); },
          (void)0, 0, 0, af01);
    PHASE({ RD_A23(0); RD_B(0, 3); }, (void)0, (void)0, 0, 3, af01);
    PHASE({}, { STB(0, 0, k2); STB(0, 1, k2); STB(0, 2, k2); },
          (void)0, 2, 3, af23);
    PHASE({}, { STB(0, 3, k2); STB(0, 4, k2); STB(0, 5, k2); },
          VMCNT6(), 2, 0, af23);
    PHASE({ RD_A01(1); RD_B(1, 0); }, { STA(0, 0, k2); STA(0, 1, k2); },
          (void)0, 0, 0, af01);
    PHASE({ RD_A23(1); RD_B(1, 3); }, (void)0, (void)0, 0, 3, af01);
    PHASE({}, { STB(1, 0, k3); STB(1, 1, k3); STB(1, 2, k3); },
          (void)0, 2, 3, af23);
    PHASE({}, { STB(1, 3, k3); STB(1, 4, k3); STB(1, 5, k3); },
          VMCNT6(), 2, 0, af23);
  }
#undef PHASE
#undef MQ
#undef RD_A01
#undef RD_A23
#undef RD_B

  const int cr = l4 * 4;
#pragma unroll
  for (int n = 0; n < 6; ++n) {
    int col = colBase + wc * 96 + n * 16 + l15;
    float bv = bias[col];
#pragma unroll
    for (int m = 0; m < 4; ++m) {
      int row = rowBase + wr * 64 + m * 16 + cr;
#pragma unroll
      for (int i = 0; i < 4; ++i)
        C[(size_t)(row + i) * ldc + col] = f2bf(acc[m][n][i] + bv);
    }
  }
}

// ---------------- g1: 256x256 8-phase GEMM, S = (k@q^T)*scale, causal skip ----
__global__ __launch_bounds__(512, 2) void gemm_s(
    const unsigned short* __restrict__ A, int lda, long long sA,
    const unsigned short* __restrict__ B, int ldb, long long sB,
    unsigned short* __restrict__ C, int ldc, long long sC,
    float scale, int K) {
  int bx = blockIdx.x, by = blockIdx.y;
  const int bz = blockIdx.z;
  if (bx > by) return;
  A += (size_t)bz * sA;
  B += (size_t)bz * sB;
  const int rowBase = by * 256;
  const int colBase = bx * 256;
  const int nk = K / 64;

  __shared__ __align__(16) unsigned char lds[131072];
  const int tid = threadIdx.x;
  const int lane = tid & 63;
  const int wid = tid >> 6;
  const int wr = wid >> 2;
  const int wc = wid & 3;
  const int l15 = lane & 15, l4 = lane >> 4, l7 = lane & 7;

  f32x4 acc[8][4] = {};
  bf16x8 af0[4][2], af1[4][2], bf0[2][2], bf1[2][2];

  const unsigned short* Ab = A + (size_t)rowBase * lda;
  const unsigned short* Bb = B + (size_t)colBase * ldb;
  unsigned loff[2][2];
  unsigned lldso[2];
#pragma unroll
  for (int i = 0; i < 2; ++i) {
    int off = (i * 512 + tid) * 16;
    int r = off >> 7;
    int sb = ((off >> 4) & 7) ^ (r & 7);
    lldso[i] = (unsigned)off;
#pragma unroll
    for (int hh = 0; hh < 2; ++hh)
      loff[hh][i] = (unsigned)((hh * 128 + r) * lda + sb * 8);
  }

  auto STAGE = [&](int bufc, int isB, int half, const unsigned short* Gb, int koff) {
#pragma unroll
    for (int i = 0; i < 2; ++i)
      async16(Gb + (size_t)(loff[half][i] + (unsigned)koff),
              lds + bufc * 65536 + isB * 32768 + half * 16384 + lldso[i]);
  };
  auto RDA = [&](int bufc, int m, int kk) -> bf16x8 {
    int row = m * 16 + l15;
    int blk = (kk * 4 + l4) ^ l7;
    return *(const bf16x8*)(lds + bufc * 65536 + wr * 16384 + row * 128 + blk * 16);
  };
  auto RDB = [&](int bufc, int n, int kk) -> bf16x8 {
    int row = (wc & 1) * 64 + n * 16 + l15;
    int blk = (kk * 4 + l4) ^ l7;
    return *(const bf16x8*)(lds + bufc * 65536 + 32768 + (wc >> 1) * 16384 +
                            row * 128 + blk * 16);
  };

#define RDA8(dst, BUF, Q)                                                      \
  _Pragma("unroll") for (int mi = 0; mi < 4; ++mi)                             \
  _Pragma("unroll") for (int kk = 0; kk < 2; ++kk)                             \
      dst[mi][kk] = RDA((BUF), (Q) * 4 + mi, kk)
#define RDB4(dst, BUF, NB)                                                     \
  _Pragma("unroll") for (int nj = 0; nj < 2; ++nj)                             \
  _Pragma("unroll") for (int kk = 0; kk < 2; ++kk)                             \
      dst[nj][kk] = RDB((BUF), (NB) + nj, kk)

#define MFMAQ(MB, NB, AF, BF)                                                  \
  _Pragma("unroll") for (int kk = 0; kk < 2; ++kk)                             \
  _Pragma("unroll") for (int mi = 0; mi < 4; ++mi)                             \
  _Pragma("unroll") for (int nj = 0; nj < 2; ++nj)                             \
      acc[(MB) + mi][(NB) + nj] = __builtin_amdgcn_mfma_f32_16x16x32_bf16(     \
          AF[mi][kk], BF[nj][kk], acc[(MB) + mi][(NB) + nj], 0, 0, 0)

#define PH(RDS, STG, HINT, GATE, MB, NB, AF, BF)                               \
  do {                                                                         \
    RDS;                                                                       \
    STG;                                                                       \
    HINT;                                                                      \
    BARM();                                                                    \
    LGKM0();                                                                   \
    SCHEDB();                                                                  \
    __builtin_amdgcn_s_setprio(1);                                             \
    MFMAQ(MB, NB, AF, BF);                                                     \
    __builtin_amdgcn_s_setprio(0);                                             \
    GATE;                                                                      \
    BARM();                                                                    \
  } while (0)

  STAGE(0, 0, 0, Ab, 0);
  STAGE(0, 0, 1, Ab, 0);
  STAGE(0, 1, 0, Bb, 0);
  STAGE(0, 1, 1, Bb, 0);
  STAGE(1, 1, 0, Bb, 64);
  STAGE(1, 1, 1, Bb, 64);
  VMCNT4();
  BARM();

  const int nt2 = nk >> 1;
  for (int it = 0; it < nt2; ++it) {
    int t = it * 2;
    int kA1 = (t + 1) * 64;
    int k2 = (t + 2 < nk - 1 ? t + 2 : nk - 1) * 64;
    int k3 = (t + 3 < nk - 1 ? t + 3 : nk - 1) * 64;
    PH({ RDA8(af0, 0, 0); RDB4(bf0, 0, 0); }, STAGE(1, 0, 0, Ab, kA1), LGKM8(),
       (void)0, 0, 0, af0, bf0);
    PH({ RDB4(bf1, 0, 2); }, STAGE(1, 0, 1, Ab, kA1), (void)0,
       (void)0, 0, 2, af0, bf1);
    PH({ RDA8(af1, 0, 1); }, STAGE(0, 1, 0, Bb, k2), (void)0,
       (void)0, 4, 2, af1, bf1);
    PH({}, STAGE(0, 1, 1, Bb, k2), (void)0,
       VMCNT4(), 4, 0, af1, bf0);
    PH({ RDA8(af0, 1, 0); RDB4(bf0, 1, 0); }, STAGE(0, 0, 0, Ab, k2), LGKM8(),
       (void)0, 0, 0, af0, bf0);
    PH({ RDB4(bf1, 1, 2); }, STAGE(0, 0, 1, Ab, k2), (void)0,
       (void)0, 0, 2, af0, bf1);
    PH({ RDA8(af1, 1, 1); }, STAGE(1, 1, 0, Bb, k3), (void)0,
       (void)0, 4, 2, af1, bf1);
    PH({}, STAGE(1, 1, 1, Bb, k3), (void)0,
       VMCNT4(), 4, 0, af1, bf0);
  }
#undef PH
#undef MFMAQ
#undef RDA8
#undef RDB4

  const int cr = l4 * 4;
  unsigned short* Cb = C + (size_t)bz * sC;
#pragma unroll
  for (int n = 0; n < 4; ++n) {
    int col = colBase + wc * 64 + n * 16 + l15;
#pragma unroll
    for (int m = 0; m < 8; ++m) {
      int row = rowBase + wr * 128 + m * 16 + cr;
#pragma unroll
      for (int i = 0; i < 4; ++i)
        Cb[(size_t)(row + i) * ldc + col] = f2bf(acc[m][n][i] * scale);
    }
  }
}

// ---------------- g2: out = P @ vT^T, 128x128 BK=64, 2-3 blocks/CU ------------
// Single-buffer 2-barrier engine (r1-proven; __syncthreads drains vmcnt).
// 512 blocks, K truncated at diagonal, heavy chains dispatched first.
// Small LDS (32KB) + ~150 VGPR -> multiple resident blocks drift out of phase
// and overlap staging/MFMA across blocks (m114 mechanism).
__global__ __launch_bounds__(256, 2) void gemm_pv(
    const unsigned short* __restrict__ S, const unsigned short* __restrict__ V,
    float* __restrict__ O) {
  const int bx = blockIdx.x;
  const int by = 15 - (int)blockIdx.y;   // heavy (long-K) chains first
  const int bz = blockIdx.z;
  const unsigned short* A = S + (size_t)bz * 2048 * 2048 + (size_t)(by * 128) * 2048;
  const unsigned short* B = V + (size_t)bz * 1024 * 2048 + (size_t)(bx * 128) * 2048;
  float* Ob = O + (size_t)bz * 2048 * 1024;
  const int nk = (by + 1) * 2;           // K-tiles of 64 (causal truncation)

  __shared__ __align__(16) unsigned char lds[32768];  // A 16KB | B 16KB
  const int tid = threadIdx.x;
  const int lane = tid & 63, wid = tid >> 6;
  const int wr = (wid >> 1) * 64, wc = (wid & 1) * 64;
  const int l15 = lane & 15, l4 = lane >> 4, l7 = lane & 7;

  f32x4 acc[4][4] = {};

  unsigned goff[4], ldso[4];
#pragma unroll
  for (int i = 0; i < 4; ++i) {
    int off = (i * 256 + tid) * 16;
    int r = off >> 7;                       // row (128B = 64 bf16 per row)
    int sb = ((off >> 4) & 7) ^ (r & 7);    // pre-swizzled source block
    goff[i] = (unsigned)(r * 2048 + sb * 8);
    ldso[i] = (unsigned)off;
  }

  for (int kt = 0; kt < nk; ++kt) {
    const unsigned kof = (unsigned)(kt * 64);
    __syncthreads();
#pragma unroll
    for (int i = 0; i < 4; ++i) {
      async16(A + (size_t)(goff[i] + kof), lds + ldso[i]);
      async16(B + (size_t)(goff[i] + kof), lds + 16384 + ldso[i]);
    }
    __syncthreads();
    bf16x8 af[4][2], bfr[4][2];
#pragma unroll
    for (int m = 0; m < 4; ++m) {
      int row = wr + m * 16 + l15;
#pragma unroll
      for (int kk = 0; kk < 2; ++kk)
        af[m][kk] = *(const bf16x8*)(lds + row * 128 + (((kk * 4 + l4) ^ l7) * 16));
    }
#pragma unroll
    for (int n = 0; n < 4; ++n) {
      int row = wc + n * 16 + l15;
#pragma unroll
      for (int kk = 0; kk < 2; ++kk)
        bfr[n][kk] = *(const bf16x8*)(lds + 16384 + row * 128 + (((kk * 4 + l4) ^ l7) * 16));
    }
#pragma unroll
    for (int kk = 0; kk < 2; ++kk)
#pragma unroll
      for (int m = 0; m < 4; ++m)
#pragma unroll
        for (int n = 0; n < 4; ++n)
          acc[m][n] = __builtin_amdgcn_mfma_f32_16x16x32_bf16(af[m][kk], bfr[n][kk],
                                                              acc[m][n], 0, 0, 0);
  }

  const int cr = l4 * 4;
#pragma unroll
  for (int n = 0; n < 4; ++n) {
    int col = bx * 128 + wc + n * 16 + l15;
#pragma unroll
    for (int m = 0; m < 4; ++m) {
      int row = by * 128 + wr + m * 16 + cr;
#pragma unroll
      for (int i = 0; i < 4; ++i)
        Ob[(size_t)(row + i) * 1024 + col] = acc[m][n][i];
    }
  }
}

// ---------------- causal softmax over S rows (in place, bf16) ----------------
// Loads cols < nv; stores cols < bound = ceil128(t+1) — exactly the K-range
// gemm_pv's 128-tile truncation reads (zero-fills masked remainder).
__global__ __launch_bounds__(256) void softmax_causal(unsigned short* __restrict__ S) {
  const int T = 2048;
  int t = blockIdx.x, b = blockIdx.y;
  unsigned short* row = S + ((size_t)b * T + t) * T;
  const int nv = t + 1;
  const int bound = ((t >> 7) + 1) << 7;
  int tid = threadIdx.x;
  int lane = tid & 63, wid = tid >> 6;
  int s0 = tid * 8;
  us8 raw = {};
  if (s0 < nv) raw = *(const us8*)(row + s0);
  float v[8];
  float m = -3.0e38f;
#pragma unroll
  for (int j = 0; j < 8; ++j) {
    v[j] = bf2f(raw[j]);
    if (s0 + j < nv) m = fmaxf(m, v[j]);
  }
#pragma unroll
  for (int o = 32; o > 0; o >>= 1) m = fmaxf(m, __shfl_xor(m, o, 64));
  __shared__ float red[4];
  if (lane == 0) red[wid] = m;
  __syncthreads();
  m = fmaxf(fmaxf(red[0], red[1]), fmaxf(red[2], red[3]));
  __syncthreads();
  float sum = 0.f;
#pragma unroll
  for (int j = 0; j < 8; ++j) {
    float e = (s0 + j < nv) ? exp2f(v[j] - m) : 0.f;
    v[j] = e;
    sum += e;
  }
#pragma unroll
  for (int o = 32; o > 0; o >>= 1) sum += __shfl_xor(sum, o, 64);
  if (lane == 0) red[wid] = sum;
  __syncthreads();
  sum = red[0] + red[1] + red[2] + red[3];
  float inv = 1.0f / sum;
  if (s0 < bound) {
    us8 outv;
#pragma unroll
    for (int j = 0; j < 8; ++j) outv[j] = f2bf(v[j] * inv);
    *(us8*)(row + s0) = outv;
  }
}

extern "C" void kernel_launch(void* const* d_in, const int* in_sizes, int n_in,
                              void* d_out, int out_size, void* d_ws, size_t ws_size,
                              hipStream_t stream) {
  const float* x = (const float*)d_in[0];      // [4,2048,1024]
  const float* W = (const float*)d_in[1];      // [3072,1024]
  const float* bias = (const float*)d_in[2];   // [3072]
  float* out = (float*)d_out;                  // [4,2048,1024]

  char* ws = (char*)d_ws;
  if (ws_size < 106954752u) return;
  unsigned short* xbf = (unsigned short*)(ws);
  unsigned short* vT = xbf;  // alias: xbf dead after gemm_g0
  unsigned short* wbf = (unsigned short*)(ws + 16777216);
  unsigned short* kqv = (unsigned short*)(ws + 23068672);
  unsigned short* S = (unsigned short*)(ws + 73400320);

  const float kSoftmaxScale = 1.4426950408889634f / 32.0f;  // log2(e)/sqrt(1024)

  cvt_bf16_2<<<11264, 256, 0, stream>>>(x, xbf, 2097152, W, wbf, 786432);

  // kqv = x @ W^T + b : 128x384 tiles, 8x64 = 512 blocks = 2 exact rounds
  gemm_g0<<<dim3(512, 1, 1), 512, 0, stream>>>(xbf, wbf, kqv, bias);

  transpose_v<<<dim3(32, 16, 4), 256, 0, stream>>>(kqv, vT);

  // S = (k @ q^T) * log2e/32 (bf16), causal blocks skipped
  gemm_s<<<dim3(8, 8, 4), 512, 0, stream>>>(
      kqv, 3072, 2048LL * 3072, kqv + 1024, 3072, 2048LL * 3072,
      S, 2048, 2048LL * 2048, kSoftmaxScale, 1024);

  softmax_causal<<<dim3(2048, 4), 256, 0, stream>>>(S);

  // out = P @ vT^T (fp32), 128^2/BK64 tiles, K truncated, heavy-first, 512 blocks
  gemm_pv<<<dim3(8, 16, 4), 256, 0, stream>>>(S, vT, out);
}

// Round 12
// 170.699 us; speedup vs baseline: 1.1737x; 1.0036x over previous
//
#include <hip/hip_runtime.h>

typedef __bf16 bf16x8 __attribute__((ext_vector_type(8)));
typedef float f32x4 __attribute__((ext_vector_type(4)));
typedef float fl4 __attribute__((ext_vector_type(4)));
typedef unsigned short us4 __attribute__((ext_vector_type(4)));
typedef unsigned short us8 __attribute__((ext_vector_type(8)));

__device__ __forceinline__ unsigned short f2bf(float f) {
  unsigned u = __builtin_bit_cast(unsigned, f);
  u += 0x7fffu + ((u >> 16) & 1u);
  return (unsigned short)(u >> 16);
}
__device__ __forceinline__ float bf2f(unsigned short h) {
  unsigned u = ((unsigned)h) << 16;
  return __builtin_bit_cast(float, u);
}

__device__ __forceinline__ void async16(const void* g, void* l) {
  __builtin_amdgcn_global_load_lds(
      (const __attribute__((address_space(1))) unsigned int*)g,
      (__attribute__((address_space(3))) unsigned int*)l, 16, 0, 0);
}

#define BARM() asm volatile("s_barrier" ::: "memory")
#define VMCNT4() asm volatile("s_waitcnt vmcnt(4)" ::: "memory")
#define VMCNT6() asm volatile("s_waitcnt vmcnt(6)" ::: "memory")
#define LGKM0() asm volatile("s_waitcnt lgkmcnt(0)" ::: "memory")
#define LGKM8() asm volatile("s_waitcnt lgkmcnt(8)" ::: "memory")
#define SCHEDB() __builtin_amdgcn_sched_barrier(0)

// ---------------- fp32 -> bf16 convert (x and W merged) ----------------
__global__ __launch_bounds__(256) void cvt_bf16_2(const float* __restrict__ sA,
                                                  unsigned short* __restrict__ dA, int nA,
                                                  const float* __restrict__ sB,
                                                  unsigned short* __restrict__ dB, int nB) {
  int i = blockIdx.x * 256 + threadIdx.x;
  const float* s;
  unsigned short* d;
  if (i < nA) {
    s = sA; d = dA;
  } else {
    i -= nA;
    if (i >= nB) return;
    s = sB; d = dB;
  }
  fl4 f = ((const fl4*)s)[i];
  us4 o;
  o[0] = f2bf(f[0]); o[1] = f2bf(f[1]); o[2] = f2bf(f[2]); o[3] = f2bf(f[3]);
  ((us4*)d)[i] = o;
}

// ---------------- g0: 128x384 8-phase GEMM, 512 blocks = 2 exact rounds -------
__global__ __launch_bounds__(512, 2) void gemm_g0(
    const unsigned short* __restrict__ A, const unsigned short* __restrict__ B,
    unsigned short* __restrict__ C, const float* __restrict__ bias) {
  const int flat = blockIdx.x;
  const int swz = (flat & 7) * 64 + (flat >> 3);   // XCD-contiguous remap
  const int bx = swz & 7;
  const int by = swz >> 3;
  const int rowBase = by * 128, colBase = bx * 384;
  const int lda = 1024, ldc = 3072, nk = 16;

  __shared__ __align__(16) unsigned char lds[131072];
  const int tid = threadIdx.x;
  const int lane = tid & 63, wid = tid >> 6;
  const int wr = wid >> 2, wc = wid & 3;
  const int l15 = lane & 15, l4 = lane >> 4, l7 = lane & 7;

  f32x4 acc[4][6] = {};
  bf16x8 af01[2][2], af23[2][2], bf[6][2];

  const unsigned short* Ab = A + (size_t)rowBase * lda;
  const unsigned short* Bb = B + (size_t)colBase * lda;
  unsigned aoff[2], boff[6], aldso[2], bldso[6];
#pragma unroll
  for (int i = 0; i < 6; ++i) {
    int off = i * 8192 + tid * 16;
    int r = off >> 7;
    int sb = ((off >> 4) & 7) ^ (r & 7);
    if (i < 2) { aoff[i] = (unsigned)(r * lda + sb * 8); aldso[i] = (unsigned)off; }
    boff[i] = (unsigned)(r * lda + sb * 8);
    bldso[i] = (unsigned)off;
  }

  auto STA = [&](int bufc, int op, int koff) {
    async16(Ab + (size_t)(aoff[op] + (unsigned)koff), lds + bufc * 65536 + aldso[op]);
  };
  auto STB = [&](int bufc, int op, int koff) {
    async16(Bb + (size_t)(boff[op] + (unsigned)koff),
            lds + bufc * 65536 + 16384 + bldso[op]);
  };
  auto RA = [&](int bufc, int m, int kk) -> bf16x8 {
    int row = wr * 64 + m * 16 + l15;
    int blk = (kk * 4 + l4) ^ l7;
    return *(const bf16x8*)(lds + bufc * 65536 + row * 128 + blk * 16);
  };
  auto RB = [&](int bufc, int n, int kk) -> bf16x8 {
    int row = wc * 96 + n * 16 + l15;
    int blk = (kk * 4 + l4) ^ l7;
    return *(const bf16x8*)(lds + bufc * 65536 + 16384 + row * 128 + blk * 16);
  };

#define RD_A01(BUF)                                                            \
  _Pragma("unroll") for (int mi = 0; mi < 2; ++mi)                             \
  _Pragma("unroll") for (int kk = 0; kk < 2; ++kk) af01[mi][kk] = RA((BUF), mi, kk)
#define RD_A23(BUF)                                                            \
  _Pragma("unroll") for (int mi = 0; mi < 2; ++mi)                             \
  _Pragma("unroll") for (int kk = 0; kk < 2; ++kk) af23[mi][kk] = RA((BUF), 2 + mi, kk)
#define RD_B(BUF, N0)                                                          \
  _Pragma("unroll") for (int nj = 0; nj < 3; ++nj)                             \
  _Pragma("unroll") for (int kk = 0; kk < 2; ++kk) bf[(N0) + nj][kk] = RB((BUF), (N0) + nj, kk)

#define MQ(MB, NB, AF)                                                         \
  _Pragma("unroll") for (int kk = 0; kk < 2; ++kk)                             \
  _Pragma("unroll") for (int mi = 0; mi < 2; ++mi)                             \
  _Pragma("unroll") for (int nj = 0; nj < 3; ++nj)                             \
      acc[(MB) + mi][(NB) + nj] = __builtin_amdgcn_mfma_f32_16x16x32_bf16(     \
          AF[mi][kk], bf[(NB) + nj][kk], acc[(MB) + mi][(NB) + nj], 0, 0, 0)

#define PHASE(RDS, STG, GATE, MB, NB, AF)                                      \
  do {                                                                         \
    RDS;                                                                       \
    STG;                                                                       \
    BARM();                                                                    \
    LGKM0();                                                                   \
    SCHEDB();                                                                  \
    __builtin_amdgcn_s_setprio(1);                                             \
    MQ(MB, NB, AF);                                                            \
    __builtin_amdgcn_s_setprio(0);                                             \
    GATE;                                                                      \
    BARM();                                                                    \
  } while (0)

  STA(0, 0, 0); STA(0, 1, 0);
#pragma unroll
  for (int i = 0; i < 6; ++i) STB(0, i, 0);
#pragma unroll
  for (int i = 0; i < 6; ++i) STB(1, i, 64);
  VMCNT6();
  BARM();

  for (int it = 0; it < 8; ++it) {
    int t = it * 2;
    int kA1 = (t + 1) * 64;
    int k2 = (t + 2 < nk - 1 ? t + 2 : nk - 1) * 64;
    int k3 = (t + 3 < nk - 1 ? t + 3 : nk - 1) * 64;
    PHASE({ RD_A01(0); RD_B(0, 0); }, { STA(1, 0, kA1); STA(1, 1, kA1); },
          (void)0, 0, 0, af01);
    PHASE({ RD_A23(0); RD_B(0, 3); }, (void)0, (void)0, 0, 3, af01);
    PHASE({}, { STB(0, 0, k2); STB(0, 1, k2); STB(0, 2, k2); },
          (void)0, 2, 3, af23);
    PHASE({}, { STB(0, 3, k2); STB(0, 4, k2); STB(0, 5, k2); },
          VMCNT6(), 2, 0, af23);
    PHASE({ RD_A01(1); RD_B(1, 0); }, { STA(0, 0, k2); STA(0, 1, k2); },
          (void)0, 0, 0, af01);
    PHASE({ RD_A23(1); RD_B(1, 3); }, (void)0, (void)0, 0, 3, af01);
    PHASE({}, { STB(1, 0, k3); STB(1, 1, k3); STB(1, 2, k3); },
          (void)0, 2, 3, af23);
    PHASE({}, { STB(1, 3, k3); STB(1, 4, k3); STB(1, 5, k3); },
          VMCNT6(), 2, 0, af23);
  }
#undef PHASE
#undef MQ
#undef RD_A01
#undef RD_A23
#undef RD_B

  const int cr = l4 * 4;
#pragma unroll
  for (int n = 0; n < 6; ++n) {
    int col = colBase + wc * 96 + n * 16 + l15;
    float bv = bias[col];
#pragma unroll
    for (int m = 0; m < 4; ++m) {
      int row = rowBase + wr * 64 + m * 16 + cr;
#pragma unroll
      for (int i = 0; i < 4; ++i)
        C[(size_t)(row + i) * ldc + col] = f2bf(acc[m][n][i] + bv);
    }
  }
}

// ---------------- fused: gemm_s (blocks 0..255) + transpose_v (blocks 256+) ---
// Both depend only on kqv (g0 output) — co-dispatched so transpose fills the
// CUs left idle by gemm_s's 144 live blocks (112 causal-dead exit instantly).
__global__ __launch_bounds__(512, 2) void g1_fused(
    const unsigned short* __restrict__ kqv, unsigned short* __restrict__ S,
    unsigned short* __restrict__ vT, float scale) {
  __shared__ __align__(16) unsigned char lds[131072];
  const int f = blockIdx.x;
  const int tid = threadIdx.x;

  if (f >= 256) {
    // ---- transpose tile: vT[b][c][t] = kqv[b*2048+t][2048+c], 64x64 ----
    int i = f - 256;               // 0..2047
    int bz = i >> 9;
    int r = i & 511;
    int t0 = (r >> 4) * 64;
    int c0 = (r & 15) * 64;
    unsigned short* tile = (unsigned short*)lds;   // [64][68]
#pragma unroll
    for (int it = 0; it < 2; ++it) {
      int idx = it * 512 + tid;
      int rr = idx >> 4;
      int c4 = (idx & 15) * 4;
      const unsigned short* src =
          kqv + ((size_t)(bz * 2048 + t0 + rr)) * 3072 + 2048 + c0 + c4;
      us4 v = *(const us4*)src;
      *(us4*)&tile[rr * 68 + c4] = v;
    }
    __syncthreads();
#pragma unroll
    for (int it = 0; it < 2; ++it) {
      int idx = it * 512 + tid;
      int rc = idx >> 4;
      int t4 = (idx & 15) * 4;
      us4 v;
      v[0] = tile[(t4 + 0) * 68 + rc]; v[1] = tile[(t4 + 1) * 68 + rc];
      v[2] = tile[(t4 + 2) * 68 + rc]; v[3] = tile[(t4 + 3) * 68 + rc];
      unsigned short* dst = vT + ((size_t)(bz * 1024 + c0 + rc)) * 2048 + t0 + t4;
      *(us4*)dst = v;
    }
    return;
  }

  // ---- gemm_s: S = (k @ q^T) * scale, 256x256 8-phase, causal skip ----
  const int bz = f >> 6;
  const int rr = f & 63;
  const int bx = rr & 7;
  const int by = rr >> 3;
  if (bx > by) return;
  const unsigned short* A = kqv + (size_t)bz * 2048 * 3072;
  const unsigned short* B = A + 1024;
  const int lda = 3072;
  const int rowBase = by * 256;
  const int colBase = bx * 256;
  const int nk = 16;

  const int lane = tid & 63;
  const int wid = tid >> 6;
  const int wr = wid >> 2;
  const int wc = wid & 3;
  const int l15 = lane & 15, l4 = lane >> 4, l7 = lane & 7;

  f32x4 acc[8][4] = {};
  bf16x8 af0[4][2], af1[4][2], bf0[2][2], bf1[2][2];

  const unsigned short* Ab = A + (size_t)rowBase * lda;
  const unsigned short* Bb = B + (size_t)colBase * lda;
  unsigned loff[2][2];
  unsigned lldso[2];
#pragma unroll
  for (int i = 0; i < 2; ++i) {
    int off = (i * 512 + tid) * 16;
    int r = off >> 7;
    int sb = ((off >> 4) & 7) ^ (r & 7);
    lldso[i] = (unsigned)off;
#pragma unroll
    for (int hh = 0; hh < 2; ++hh)
      loff[hh][i] = (unsigned)((hh * 128 + r) * lda + sb * 8);
  }

  auto STAGE = [&](int bufc, int isB, int half, const unsigned short* Gb, int koff) {
#pragma unroll
    for (int i = 0; i < 2; ++i)
      async16(Gb + (size_t)(loff[half][i] + (unsigned)koff),
              lds + bufc * 65536 + isB * 32768 + half * 16384 + lldso[i]);
  };
  auto RDA = [&](int bufc, int m, int kk) -> bf16x8 {
    int row = m * 16 + l15;
    int blk = (kk * 4 + l4) ^ l7;
    return *(const bf16x8*)(lds + bufc * 65536 + wr * 16384 + row * 128 + blk * 16);
  };
  auto RDB = [&](int bufc, int n, int kk) -> bf16x8 {
    int row = (wc & 1) * 64 + n * 16 + l15;
    int blk = (kk * 4 + l4) ^ l7;
    return *(const bf16x8*)(lds + bufc * 65536 + 32768 + (wc >> 1) * 16384 +
                            row * 128 + blk * 16);
  };

#define RDA8(dst, BUF, Q)                                                      \
  _Pragma("unroll") for (int mi = 0; mi < 4; ++mi)                             \
  _Pragma("unroll") for (int kk = 0; kk < 2; ++kk)                             \
      dst[mi][kk] = RDA((BUF), (Q) * 4 + mi, kk)
#define RDB4(dst, BUF, NB)                                                     \
  _Pragma("unroll") for (int nj = 0; nj < 2; ++nj)                             \
  _Pragma("unroll") for (int kk = 0; kk < 2; ++kk)                             \
      dst[nj][kk] = RDB((BUF), (NB) + nj, kk)

#define MFMAQ(MB, NB, AF, BF)                                                  \
  _Pragma("unroll") for (int kk = 0; kk < 2; ++kk)                             \
  _Pragma("unroll") for (int mi = 0; mi < 4; ++mi)                             \
  _Pragma("unroll") for (int nj = 0; nj < 2; ++nj)                             \
      acc[(MB) + mi][(NB) + nj] = __builtin_amdgcn_mfma_f32_16x16x32_bf16(     \
          AF[mi][kk], BF[nj][kk], acc[(MB) + mi][(NB) + nj], 0, 0, 0)

#define PH(RDS, STG, HINT, GATE, MB, NB, AF, BF)                               \
  do {                                                                         \
    RDS;                                                                       \
    STG;                                                                       \
    HINT;                                                                      \
    BARM();                                                                    \
    LGKM0();                                                                   \
    SCHEDB();                                                                  \
    __builtin_amdgcn_s_setprio(1);                                             \
    MFMAQ(MB, NB, AF, BF);                                                     \
    __builtin_amdgcn_s_setprio(0);                                             \
    GATE;                                                                      \
    BARM();                                                                    \
  } while (0)

  STAGE(0, 0, 0, Ab, 0);
  STAGE(0, 0, 1, Ab, 0);
  STAGE(0, 1, 0, Bb, 0);
  STAGE(0, 1, 1, Bb, 0);
  STAGE(1, 1, 0, Bb, 64);
  STAGE(1, 1, 1, Bb, 64);
  VMCNT4();
  BARM();

  const int nt2 = nk >> 1;
  for (int it = 0; it < nt2; ++it) {
    int t = it * 2;
    int kA1 = (t + 1) * 64;
    int k2 = (t + 2 < nk - 1 ? t + 2 : nk - 1) * 64;
    int k3 = (t + 3 < nk - 1 ? t + 3 : nk - 1) * 64;
    PH({ RDA8(af0, 0, 0); RDB4(bf0, 0, 0); }, STAGE(1, 0, 0, Ab, kA1), LGKM8(),
       (void)0, 0, 0, af0, bf0);
    PH({ RDB4(bf1, 0, 2); }, STAGE(1, 0, 1, Ab, kA1), (void)0,
       (void)0, 0, 2, af0, bf1);
    PH({ RDA8(af1, 0, 1); }, STAGE(0, 1, 0, Bb, k2), (void)0,
       (void)0, 4, 2, af1, bf1);
    PH({}, STAGE(0, 1, 1, Bb, k2), (void)0,
       VMCNT4(), 4, 0, af1, bf0);
    PH({ RDA8(af0, 1, 0); RDB4(bf0, 1, 0); }, STAGE(0, 0, 0, Ab, k2), LGKM8(),
       (void)0, 0, 0, af0, bf0);
    PH({ RDB4(bf1, 1, 2); }, STAGE(0, 0, 1, Ab, k2), (void)0,
       (void)0, 0, 2, af0, bf1);
    PH({ RDA8(af1, 1, 1); }, STAGE(1, 1, 0, Bb, k3), (void)0,
       (void)0, 4, 2, af1, bf1);
    PH({}, STAGE(1, 1, 1, Bb, k3), (void)0,
       VMCNT4(), 4, 0, af1, bf0);
  }
#undef PH
#undef MFMAQ
#undef RDA8
#undef RDB4

  const int cr = l4 * 4;
  unsigned short* Cb = S + (size_t)bz * 2048 * 2048;
#pragma unroll
  for (int n = 0; n < 4; ++n) {
    int col = colBase + wc * 64 + n * 16 + l15;
#pragma unroll
    for (int m = 0; m < 8; ++m) {
      int row = rowBase + wr * 128 + m * 16 + cr;
#pragma unroll
      for (int i = 0; i < 4; ++i)
        Cb[(size_t)(row + i) * 2048 + col] = f2bf(acc[m][n][i] * scale);
    }
  }
}

// ---------------- g2: out = P @ vT^T, 128x128 BK=64, complementary pairing ----
// 512 blocks = exactly 2/CU. Block f and f+256 share (bx,bz,p) with by = 15-p
// and by = p: per-CU chain sum = 34 K-tiles (uniform) and the light partner
// re-reads the same V panel (L2-hot). Heavy half dispatched first.
__global__ __launch_bounds__(256, 2) void gemm_pv(
    const unsigned short* __restrict__ S, const unsigned short* __restrict__ V,
    float* __restrict__ O) {
  const int f = blockIdx.x;
  const int halfsel = f >> 8;            // 0: heavy half, 1: light half
  const int i = f & 255;
  const int bz = i >> 6;
  const int r = i & 63;
  const int bx = r & 7;
  const int p = r >> 3;
  const int by = halfsel ? p : (15 - p);
  const unsigned short* A = S + (size_t)bz * 2048 * 2048 + (size_t)(by * 128) * 2048;
  const unsigned short* B = V + (size_t)bz * 1024 * 2048 + (size_t)(bx * 128) * 2048;
  float* Ob = O + (size_t)bz * 2048 * 1024;
  const int nk = (by + 1) * 2;           // K-tiles of 64 (causal truncation)

  __shared__ __align__(16) unsigned char lds[32768];  // A 16KB | B 16KB
  const int tid = threadIdx.x;
  const int lane = tid & 63, wid = tid >> 6;
  const int wr = (wid >> 1) * 64, wc = (wid & 1) * 64;
  const int l15 = lane & 15, l4 = lane >> 4, l7 = lane & 7;

  f32x4 acc[4][4] = {};

  unsigned goff[4], ldso[4];
#pragma unroll
  for (int ii = 0; ii < 4; ++ii) {
    int off = (ii * 256 + tid) * 16;
    int rr = off >> 7;
    int sb = ((off >> 4) & 7) ^ (rr & 7);
    goff[ii] = (unsigned)(rr * 2048 + sb * 8);
    ldso[ii] = (unsigned)off;
  }

  for (int kt = 0; kt < nk; ++kt) {
    const unsigned kof = (unsigned)(kt * 64);
    __syncthreads();
#pragma unroll
    for (int ii = 0; ii < 4; ++ii) {
      async16(A + (size_t)(goff[ii] + kof), lds + ldso[ii]);
      async16(B + (size_t)(goff[ii] + kof), lds + 16384 + ldso[ii]);
    }
    __syncthreads();
    bf16x8 af[4][2], bfr[4][2];
#pragma unroll
    for (int m = 0; m < 4; ++m) {
      int row = wr + m * 16 + l15;
#pragma unroll
      for (int kk = 0; kk < 2; ++kk)
        af[m][kk] = *(const bf16x8*)(lds + row * 128 + (((kk * 4 + l4) ^ l7) * 16));
    }
#pragma unroll
    for (int n = 0; n < 4; ++n) {
      int row = wc + n * 16 + l15;
#pragma unroll
      for (int kk = 0; kk < 2; ++kk)
        bfr[n][kk] = *(const bf16x8*)(lds + 16384 + row * 128 + (((kk * 4 + l4) ^ l7) * 16));
    }
#pragma unroll
    for (int kk = 0; kk < 2; ++kk)
#pragma unroll
      for (int m = 0; m < 4; ++m)
#pragma unroll
        for (int n = 0; n < 4; ++n)
          acc[m][n] = __builtin_amdgcn_mfma_f32_16x16x32_bf16(af[m][kk], bfr[n][kk],
                                                              acc[m][n], 0, 0, 0);
  }

  const int cr = l4 * 4;
#pragma unroll
  for (int n = 0; n < 4; ++n) {
    int col = bx * 128 + wc + n * 16 + l15;
#pragma unroll
    for (int m = 0; m < 4; ++m) {
      int row = by * 128 + wr + m * 16 + cr;
#pragma unroll
      for (int i2 = 0; i2 < 4; ++i2)
        Ob[(size_t)(row + i2) * 1024 + col] = acc[m][n][i2];
    }
  }
}

// ---------------- causal softmax over S rows (in place, bf16) ----------------
// Loads cols < nv; stores cols < bound = ceil128(t+1) — exactly the K-range
// gemm_pv's 128-tile truncation reads (zero-fills masked remainder).
__global__ __launch_bounds__(256) void softmax_causal(unsigned short* __restrict__ S) {
  const int T = 2048;
  int t = blockIdx.x, b = blockIdx.y;
  unsigned short* row = S + ((size_t)b * T + t) * T;
  const int nv = t + 1;
  const int bound = ((t >> 7) + 1) << 7;
  int tid = threadIdx.x;
  int lane = tid & 63, wid = tid >> 6;
  int s0 = tid * 8;
  us8 raw = {};
  if (s0 < nv) raw = *(const us8*)(row + s0);
  float v[8];
  float m = -3.0e38f;
#pragma unroll
  for (int j = 0; j < 8; ++j) {
    v[j] = bf2f(raw[j]);
    if (s0 + j < nv) m = fmaxf(m, v[j]);
  }
#pragma unroll
  for (int o = 32; o > 0; o >>= 1) m = fmaxf(m, __shfl_xor(m, o, 64));
  __shared__ float red[4];
  if (lane == 0) red[wid] = m;
  __syncthreads();
  m = fmaxf(fmaxf(red[0], red[1]), fmaxf(red[2], red[3]));
  __syncthreads();
  float sum = 0.f;
#pragma unroll
  for (int j = 0; j < 8; ++j) {
    float e = (s0 + j < nv) ? exp2f(v[j] - m) : 0.f;
    v[j] = e;
    sum += e;
  }
#pragma unroll
  for (int o = 32; o > 0; o >>= 1) sum += __shfl_xor(sum, o, 64);
  if (lane == 0) red[wid] = sum;
  __syncthreads();
  sum = red[0] + red[1] + red[2] + red[3];
  float inv = 1.0f / sum;
  if (s0 < bound) {
    us8 outv;
#pragma unroll
    for (int j = 0; j < 8; ++j) outv[j] = f2bf(v[j] * inv);
    *(us8*)(row + s0) = outv;
  }
}

extern "C" void kernel_launch(void* const* d_in, const int* in_sizes, int n_in,
                              void* d_out, int out_size, void* d_ws, size_t ws_size,
                              hipStream_t stream) {
  const float* x = (const float*)d_in[0];      // [4,2048,1024]
  const float* W = (const float*)d_in[1];      // [3072,1024]
  const float* bias = (const float*)d_in[2];   // [3072]
  float* out = (float*)d_out;                  // [4,2048,1024]

  char* ws = (char*)d_ws;
  if (ws_size < 106954752u) return;
  unsigned short* xbf = (unsigned short*)(ws);
  unsigned short* vT = xbf;  // alias: xbf dead after gemm_g0
  unsigned short* wbf = (unsigned short*)(ws + 16777216);
  unsigned short* kqv = (unsigned short*)(ws + 23068672);
  unsigned short* S = (unsigned short*)(ws + 73400320);

  const float kSoftmaxScale = 1.4426950408889634f / 32.0f;  // log2(e)/sqrt(1024)

  cvt_bf16_2<<<11264, 256, 0, stream>>>(x, xbf, 2097152, W, wbf, 786432);

  // kqv = x @ W^T + b : 128x384 tiles, 8x64 = 512 blocks = 2 exact rounds
  gemm_g0<<<dim3(512, 1, 1), 512, 0, stream>>>(xbf, wbf, kqv, bias);

  // fused: S = (k@q^T)*scale (blocks 0..255) + v transpose (blocks 256..2303)
  g1_fused<<<dim3(2304, 1, 1), 512, 0, stream>>>(kqv, S, vT, kSoftmaxScale);

  softmax_causal<<<dim3(2048, 4), 256, 0, stream>>>(S);

  // out = P @ vT^T (fp32), 128^2/BK64, complementary heavy/light pairing
  gemm_pv<<<dim3(512, 1, 1), 256, 0, stream>>>(S, vT, out);
}

// Round 13
// 168.071 us; speedup vs baseline: 1.1921x; 1.0156x over previous
//
#include <hip/hip_runtime.h>

typedef __bf16 bf16x8 __attribute__((ext_vector_type(8)));
typedef float f32x4 __attribute__((ext_vector_type(4)));
typedef float fl4 __attribute__((ext_vector_type(4)));
typedef unsigned short us4 __attribute__((ext_vector_type(4)));
typedef unsigned short us8 __attribute__((ext_vector_type(8)));

__device__ __forceinline__ unsigned short f2bf(float f) {
  unsigned u = __builtin_bit_cast(unsigned, f);
  u += 0x7fffu + ((u >> 16) & 1u);
  return (unsigned short)(u >> 16);
}
__device__ __forceinline__ float bf2f(unsigned short h) {
  unsigned u = ((unsigned)h) << 16;
  return __builtin_bit_cast(float, u);
}

__device__ __forceinline__ void async16(const void* g, void* l) {
  __builtin_amdgcn_global_load_lds(
      (const __attribute__((address_space(1))) unsigned int*)g,
      (__attribute__((address_space(3))) unsigned int*)l, 16, 0, 0);
}

#define BARM() asm volatile("s_barrier" ::: "memory")
#define VMCNT4() asm volatile("s_waitcnt vmcnt(4)" ::: "memory")
#define VMCNT6() asm volatile("s_waitcnt vmcnt(6)" ::: "memory")
#define VMCNT8() asm volatile("s_waitcnt vmcnt(8)" ::: "memory")
#define LGKM0() asm volatile("s_waitcnt lgkmcnt(0)" ::: "memory")
#define LGKM8() asm volatile("s_waitcnt lgkmcnt(8)" ::: "memory")
#define SCHEDB() __builtin_amdgcn_sched_barrier(0)

// ---------------- fp32 -> bf16 convert (x and W merged) ----------------
__global__ __launch_bounds__(256) void cvt_bf16_2(const float* __restrict__ sA,
                                                  unsigned short* __restrict__ dA, int nA,
                                                  const float* __restrict__ sB,
                                                  unsigned short* __restrict__ dB, int nB) {
  int i = blockIdx.x * 256 + threadIdx.x;
  const float* s;
  unsigned short* d;
  if (i < nA) {
    s = sA; d = dA;
  } else {
    i -= nA;
    if (i >= nB) return;
    s = sB; d = dB;
  }
  fl4 f = ((const fl4*)s)[i];
  us4 o;
  o[0] = f2bf(f[0]); o[1] = f2bf(f[1]); o[2] = f2bf(f[2]); o[3] = f2bf(f[3]);
  ((us4*)d)[i] = o;
}

// ---------------- transpose v: vT[b][c][t] = kqv[b*2048+t][2048+c] ----------------
__global__ __launch_bounds__(256) void transpose_v(const unsigned short* __restrict__ kqv,
                                                   unsigned short* __restrict__ vT) {
  int b = blockIdx.z;
  int t0 = blockIdx.x * 64;
  int c0 = blockIdx.y * 64;
  __shared__ unsigned short tile[64][68];
  int tid = threadIdx.x;
#pragma unroll
  for (int i = 0; i < 4; ++i) {
    int idx = i * 256 + tid;
    int r = idx >> 4;
    int c4 = (idx & 15) * 4;
    const unsigned short* src = kqv + ((size_t)(b * 2048 + t0 + r)) * 3072 + 2048 + c0 + c4;
    us4 v = *(const us4*)src;
    *(us4*)&tile[r][c4] = v;
  }
  __syncthreads();
#pragma unroll
  for (int i = 0; i < 4; ++i) {
    int idx = i * 256 + tid;
    int rc = idx >> 4;
    int t4 = (idx & 15) * 4;
    us4 v;
    v[0] = tile[t4 + 0][rc]; v[1] = tile[t4 + 1][rc];
    v[2] = tile[t4 + 2][rc]; v[3] = tile[t4 + 3][rc];
    unsigned short* dst = vT + ((size_t)(b * 1024 + c0 + rc)) * 2048 + t0 + t4;
    *(us4*)dst = v;
  }
}

// ---------------- g0: 128x384 8-phase GEMM, 512 blocks = 2 exact rounds -------
__global__ __launch_bounds__(512, 2) void gemm_g0(
    const unsigned short* __restrict__ A, const unsigned short* __restrict__ B,
    unsigned short* __restrict__ C, const float* __restrict__ bias) {
  const int flat = blockIdx.x;
  const int swz = (flat & 7) * 64 + (flat >> 3);   // XCD-contiguous remap
  const int bx = swz & 7;
  const int by = swz >> 3;
  const int rowBase = by * 128, colBase = bx * 384;
  const int lda = 1024, ldc = 3072, nk = 16;

  __shared__ __align__(16) unsigned char lds[131072];
  const int tid = threadIdx.x;
  const int lane = tid & 63, wid = tid >> 6;
  const int wr = wid >> 2, wc = wid & 3;
  const int l15 = lane & 15, l4 = lane >> 4, l7 = lane & 7;

  f32x4 acc[4][6] = {};
  bf16x8 af01[2][2], af23[2][2], bf[6][2];

  const unsigned short* Ab = A + (size_t)rowBase * lda;
  const unsigned short* Bb = B + (size_t)colBase * lda;
  unsigned aoff[2], boff[6], aldso[2], bldso[6];
#pragma unroll
  for (int i = 0; i < 6; ++i) {
    int off = i * 8192 + tid * 16;
    int r = off >> 7;
    int sb = ((off >> 4) & 7) ^ (r & 7);
    if (i < 2) { aoff[i] = (unsigned)(r * lda + sb * 8); aldso[i] = (unsigned)off; }
    boff[i] = (unsigned)(r * lda + sb * 8);
    bldso[i] = (unsigned)off;
  }

  auto STA = [&](int bufc, int op, int koff) {
    async16(Ab + (size_t)(aoff[op] + (unsigned)koff), lds + bufc * 65536 + aldso[op]);
  };
  auto STB = [&](int bufc, int op, int koff) {
    async16(Bb + (size_t)(boff[op] + (unsigned)koff),
            lds + bufc * 65536 + 16384 + bldso[op]);
  };
  auto RA = [&](int bufc, int m, int kk) -> bf16x8 {
    int row = wr * 64 + m * 16 + l15;
    int blk = (kk * 4 + l4) ^ l7;
    return *(const bf16x8*)(lds + bufc * 65536 + row * 128 + blk * 16);
  };
  auto RB = [&](int bufc, int n, int kk) -> bf16x8 {
    int row = wc * 96 + n * 16 + l15;
    int blk = (kk * 4 + l4) ^ l7;
    return *(const bf16x8*)(lds + bufc * 65536 + 16384 + row * 128 + blk * 16);
  };

#define RD_A01(BUF)                                                            \
  _Pragma("unroll") for (int mi = 0; mi < 2; ++mi)                             \
  _Pragma("unroll") for (int kk = 0; kk < 2; ++kk) af01[mi][kk] = RA((BUF), mi, kk)
#define RD_A23(BUF)                                                            \
  _Pragma("unroll") for (int mi = 0; mi < 2; ++mi)                             \
  _Pragma("unroll") for (int kk = 0; kk < 2; ++kk) af23[mi][kk] = RA((BUF), 2 + mi, kk)
#define RD_B(BUF, N0)                                                          \
  _Pragma("unroll") for (int nj = 0; nj < 3; ++nj)                             \
  _Pragma("unroll") for (int kk = 0; kk < 2; ++kk) bf[(N0) + nj][kk] = RB((BUF), (N0) + nj, kk)

#define MQ(MB, NB, AF)                                                         \
  _Pragma("unroll") for (int kk = 0; kk < 2; ++kk)                             \
  _Pragma("unroll") for (int mi = 0; mi < 2; ++mi)                             \
  _Pragma("unroll") for (int nj = 0; nj < 3; ++nj)                             \
      acc[(MB) + mi][(NB) + nj] = __builtin_amdgcn_mfma_f32_16x16x32_bf16(     \
          AF[mi][kk], bf[(NB) + nj][kk], acc[(MB) + mi][(NB) + nj], 0, 0, 0)

#define PHASE(RDS, STG, GATE, MB, NB, AF)                                      \
  do {                                                                         \
    RDS;                                                                       \
    STG;                                                                       \
    BARM();                                                                    \
    LGKM0();                                                                   \
    SCHEDB();                                                                  \
    __builtin_amdgcn_s_setprio(1);                                             \
    MQ(MB, NB, AF);                                                            \
    __builtin_amdgcn_s_setprio(0);                                             \
    GATE;                                                                      \
    BARM();                                                                    \
  } while (0)

  STA(0, 0, 0); STA(0, 1, 0);
#pragma unroll
  for (int i = 0; i < 6; ++i) STB(0, i, 0);
#pragma unroll
  for (int i = 0; i < 6; ++i) STB(1, i, 64);
  VMCNT6();
  BARM();

  for (int it = 0; it < 8; ++it) {
    int t = it * 2;
    int kA1 = (t + 1) * 64;
    int k2 = (t + 2 < nk - 1 ? t + 2 : nk - 1) * 64;
    int k3 = (t + 3 < nk - 1 ? t + 3 : nk - 1) * 64;
    PHASE({ RD_A01(0); RD_B(0, 0); }, { STA(1, 0, kA1); STA(1, 1, kA1); },
          (void)0, 0, 0, af01);
    PHASE({ RD_A23(0); RD_B(0, 3); }, (void)0, (void)0, 0, 3, af01);
    PHASE({}, { STB(0, 0, k2); STB(0, 1, k2); STB(0, 2, k2); },
          (void)0, 2, 3, af23);
    PHASE({}, { STB(0, 3, k2); STB(0, 4, k2); STB(0, 5, k2); },
          VMCNT6(), 2, 0, af23);
    PHASE({ RD_A01(1); RD_B(1, 0); }, { STA(0, 0, k2); STA(0, 1, k2); },
          (void)0, 0, 0, af01);
    PHASE({ RD_A23(1); RD_B(1, 3); }, (void)0, (void)0, 0, 3, af01);
    PHASE({}, { STB(1, 0, k3); STB(1, 1, k3); STB(1, 2, k3); },
          (void)0, 2, 3, af23);
    PHASE({}, { STB(1, 3, k3); STB(1, 4, k3); STB(1, 5, k3); },
          VMCNT6(), 2, 0, af23);
  }
#undef PHASE
#undef MQ
#undef RD_A01
#undef RD_A23
#undef RD_B

  const int cr = l4 * 4;
#pragma unroll
  for (int n = 0; n < 6; ++n) {
    int col = colBase + wc * 96 + n * 16 + l15;
    float bv = bias[col];
#pragma unroll
    for (int m = 0; m < 4; ++m) {
      int row = rowBase + wr * 64 + m * 16 + cr;
#pragma unroll
      for (int i = 0; i < 4; ++i)
        C[(size_t)(row + i) * ldc + col] = f2bf(acc[m][n][i] + bv);
    }
  }
}

// ---------------- g1: 256x256 8-phase GEMM, S = (k@q^T)*scale, causal skip ----
__global__ __launch_bounds__(512, 2) void gemm_s(
    const unsigned short* __restrict__ A, int lda, long long sA,
    const unsigned short* __restrict__ B, int ldb, long long sB,
    unsigned short* __restrict__ C, int ldc, long long sC,
    float scale, int K) {
  int bx = blockIdx.x, by = blockIdx.y;
  const int bz = blockIdx.z;
  if (bx > by) return;
  A += (size_t)bz * sA;
  B += (size_t)bz * sB;
  const int rowBase = by * 256;
  const int colBase = bx * 256;
  const int nk = K / 64;

  __shared__ __align__(16) unsigned char lds[131072];
  const int tid = threadIdx.x;
  const int lane = tid & 63;
  const int wid = tid >> 6;
  const int wr = wid >> 2;
  const int wc = wid & 3;
  const int l15 = lane & 15, l4 = lane >> 4, l7 = lane & 7;

  f32x4 acc[8][4] = {};
  bf16x8 af0[4][2], af1[4][2], bf0[2][2], bf1[2][2];

  const unsigned short* Ab = A + (size_t)rowBase * lda;
  const unsigned short* Bb = B + (size_t)colBase * ldb;
  unsigned loff[2][2];
  unsigned lldso[2];
#pragma unroll
  for (int i = 0; i < 2; ++i) {
    int off = (i * 512 + tid) * 16;
    int r = off >> 7;
    int sb = ((off >> 4) & 7) ^ (r & 7);
    lldso[i] = (unsigned)off;
#pragma unroll
    for (int hh = 0; hh < 2; ++hh)
      loff[hh][i] = (unsigned)((hh * 128 + r) * lda + sb * 8);
  }

  auto STAGE = [&](int bufc, int isB, int half, const unsigned short* Gb, int koff) {
#pragma unroll
    for (int i = 0; i < 2; ++i)
      async16(Gb + (size_t)(loff[half][i] + (unsigned)koff),
              lds + bufc * 65536 + isB * 32768 + half * 16384 + lldso[i]);
  };
  auto RDA = [&](int bufc, int m, int kk) -> bf16x8 {
    int row = m * 16 + l15;
    int blk = (kk * 4 + l4) ^ l7;
    return *(const bf16x8*)(lds + bufc * 65536 + wr * 16384 + row * 128 + blk * 16);
  };
  auto RDB = [&](int bufc, int n, int kk) -> bf16x8 {
    int row = (wc & 1) * 64 + n * 16 + l15;
    int blk = (kk * 4 + l4) ^ l7;
    return *(const bf16x8*)(lds + bufc * 65536 + 32768 + (wc >> 1) * 16384 +
                            row * 128 + blk * 16);
  };

#define RDA8(dst, BUF, Q)                                                      \
  _Pragma("unroll") for (int mi = 0; mi < 4; ++mi)                             \
  _Pragma("unroll") for (int kk = 0; kk < 2; ++kk)                             \
      dst[mi][kk] = RDA((BUF), (Q) * 4 + mi, kk)
#define RDB4(dst, BUF, NB)                                                     \
  _Pragma("unroll") for (int nj = 0; nj < 2; ++nj)                             \
  _Pragma("unroll") for (int kk = 0; kk < 2; ++kk)                             \
      dst[nj][kk] = RDB((BUF), (NB) + nj, kk)

#define MFMAQ(MB, NB, AF, BF)                                                  \
  _Pragma("unroll") for (int kk = 0; kk < 2; ++kk)                             \
  _Pragma("unroll") for (int mi = 0; mi < 4; ++mi)                             \
  _Pragma("unroll") for (int nj = 0; nj < 2; ++nj)                             \
      acc[(MB) + mi][(NB) + nj] = __builtin_amdgcn_mfma_f32_16x16x32_bf16(     \
          AF[mi][kk], BF[nj][kk], acc[(MB) + mi][(NB) + nj], 0, 0, 0)

#define PH(RDS, STG, HINT, GATE, MB, NB, AF, BF)                               \
  do {                                                                         \
    RDS;                                                                       \
    STG;                                                                       \
    HINT;                                                                      \
    BARM();                                                                    \
    LGKM0();                                                                   \
    SCHEDB();                                                                  \
    __builtin_amdgcn_s_setprio(1);                                             \
    MFMAQ(MB, NB, AF, BF);                                                     \
    __builtin_amdgcn_s_setprio(0);                                             \
    GATE;                                                                      \
    BARM();                                                                    \
  } while (0)

  STAGE(0, 0, 0, Ab, 0);
  STAGE(0, 0, 1, Ab, 0);
  STAGE(0, 1, 0, Bb, 0);
  STAGE(0, 1, 1, Bb, 0);
  STAGE(1, 1, 0, Bb, 64);
  STAGE(1, 1, 1, Bb, 64);
  VMCNT4();
  BARM();

  const int nt2 = nk >> 1;
  for (int it = 0; it < nt2; ++it) {
    int t = it * 2;
    int kA1 = (t + 1) * 64;
    int k2 = (t + 2 < nk - 1 ? t + 2 : nk - 1) * 64;
    int k3 = (t + 3 < nk - 1 ? t + 3 : nk - 1) * 64;
    PH({ RDA8(af0, 0, 0); RDB4(bf0, 0, 0); }, STAGE(1, 0, 0, Ab, kA1), LGKM8(),
       (void)0, 0, 0, af0, bf0);
    PH({ RDB4(bf1, 0, 2); }, STAGE(1, 0, 1, Ab, kA1), (void)0,
       (void)0, 0, 2, af0, bf1);
    PH({ RDA8(af1, 0, 1); }, STAGE(0, 1, 0, Bb, k2), (void)0,
       (void)0, 4, 2, af1, bf1);
    PH({}, STAGE(0, 1, 1, Bb, k2), (void)0,
       VMCNT4(), 4, 0, af1, bf0);
    PH({ RDA8(af0, 1, 0); RDB4(bf0, 1, 0); }, STAGE(0, 0, 0, Ab, k2), LGKM8(),
       (void)0, 0, 0, af0, bf0);
    PH({ RDB4(bf1, 1, 2); }, STAGE(0, 0, 1, Ab, k2), (void)0,
       (void)0, 0, 2, af0, bf1);
    PH({ RDA8(af1, 1, 1); }, STAGE(1, 1, 0, Bb, k3), (void)0,
       (void)0, 4, 2, af1, bf1);
    PH({}, STAGE(1, 1, 1, Bb, k3), (void)0,
       VMCNT4(), 4, 0, af1, bf0);
  }
#undef PH
#undef MFMAQ
#undef RDA8
#undef RDB4

  const int cr = l4 * 4;
  unsigned short* Cb = C + (size_t)bz * sC;
#pragma unroll
  for (int n = 0; n < 4; ++n) {
    int col = colBase + wc * 64 + n * 16 + l15;
#pragma unroll
    for (int m = 0; m < 8; ++m) {
      int row = rowBase + wr * 128 + m * 16 + cr;
#pragma unroll
      for (int i = 0; i < 4; ++i)
        Cb[(size_t)(row + i) * ldc + col] = f2bf(acc[m][n][i] * scale);
    }
  }
}

// ---------------- g2: two-chain pv — uniform 34 K-tiles per block -------------
// 256 blocks = exactly 1/CU. Block (bx,p,bz) owns BOTH causal chains
// by=15-p (32-2p tiles) and by=p (2p+2 tiles): uniform load with NO scheduler
// assumptions. Double-buffered (2 x 32KB) work-item pipeline, vmcnt(8) gate
// (item s+1 always in flight); stage item s+2 into the just-consumed buffer
// AFTER the post-read barrier (reads drained via per-wave lgkmcnt(0) BEFORE
// the barrier). Tail stages clamp to item 33 (dummy re-stage keeps FIFO math).
__global__ __launch_bounds__(256, 2) void gemm_pv2(
    const unsigned short* __restrict__ S, const unsigned short* __restrict__ V,
    float* __restrict__ O) {
  const int f = blockIdx.x;
  const int bx = f & 7;
  const int p = (f >> 3) & 7;
  const int bz = f >> 6;
  const int byH = 15 - p;
  const int nkL = 2 * (p + 1);          // light chain K-tiles (BK=64)
  const int nkH = 32 - 2 * p;           // heavy chain K-tiles; nkL+nkH=34
  const unsigned short* base = S + (size_t)bz * 2048 * 2048;
  const unsigned short* AH = base + (size_t)(byH * 128) * 2048;
  const unsigned short* AL = base + (size_t)(p * 128) * 2048;
  const unsigned short* Bb = V + (size_t)bz * 1024 * 2048 + (size_t)(bx * 128) * 2048;
  float* Ob = O + (size_t)bz * 2048 * 1024;

  __shared__ __align__(16) unsigned char lds[65536];  // 2 bufs x (A16K | B16K)
  const int tid = threadIdx.x;
  const int lane = tid & 63, wid = tid >> 6;
  const int wr = (wid >> 1) * 64, wc = (wid & 1) * 64;
  const int l15 = lane & 15, l4 = lane >> 4, l7 = lane & 7;

  f32x4 accH[4][4] = {}, accL[4][4] = {};

  unsigned goff[4], ldso[4];
#pragma unroll
  for (int ii = 0; ii < 4; ++ii) {
    int off = (ii * 256 + tid) * 16;
    int rr = off >> 7;
    int sb = ((off >> 4) & 7) ^ (rr & 7);
    goff[ii] = (unsigned)(rr * 2048 + sb * 8);
    ldso[ii] = (unsigned)off;
  }

  auto ST = [&](int buf, const unsigned short* Ap, unsigned kof) {
#pragma unroll
    for (int ii = 0; ii < 4; ++ii) {
      async16(Ap + (size_t)(goff[ii] + kof), lds + buf * 32768 + ldso[ii]);
      async16(Bb + (size_t)(goff[ii] + kof), lds + buf * 32768 + 16384 + ldso[ii]);
    }
  };
  // item i (0..33): interleave region alternates H,L; then solo H.
  auto ITEM = [&](int i, const unsigned short*& P, unsigned& kf) {
    if (i < 2 * nkL) {
      P = (i & 1) ? AL : AH;
      kf = (unsigned)((i >> 1) * 64);
    } else {
      P = AH;
      kf = (unsigned)((i - nkL) * 64);
    }
  };

// step: vmcnt(8)[item ready] -> bar -> ds_read frags -> lgkm0 -> bar ->
//       stage next-next item into this buffer -> 32 MFMA into ACC.
#define PVSTEP(BUF, ACC, NITEM)                                                \
  do {                                                                         \
    const unsigned short* nP;                                                  \
    unsigned nK;                                                               \
    ITEM((NITEM) < 33 ? (NITEM) : 33, nP, nK);                                 \
    VMCNT8();                                                                  \
    BARM();                                                                    \
    bf16x8 af[4][2], bfr[4][2];                                                \
    _Pragma("unroll") for (int m = 0; m < 4; ++m) {                            \
      int row = wr + m * 16 + l15;                                             \
      _Pragma("unroll") for (int kk = 0; kk < 2; ++kk)                         \
        af[m][kk] = *(const bf16x8*)(lds + (BUF) * 32768 + row * 128 +         \
                                     (((kk * 4 + l4) ^ l7) * 16));             \
    }                                                                          \
    _Pragma("unroll") for (int n = 0; n < 4; ++n) {                            \
      int row = wc + n * 16 + l15;                                             \
      _Pragma("unroll") for (int kk = 0; kk < 2; ++kk)                         \
        bfr[n][kk] = *(const bf16x8*)(lds + (BUF) * 32768 + 16384 + row * 128 +\
                                      (((kk * 4 + l4) ^ l7) * 16));            \
    }                                                                          \
    LGKM0();                                                                   \
    BARM();                                                                    \
    ST((BUF), nP, nK);                                                         \
    SCHEDB();                                                                  \
    __builtin_amdgcn_s_setprio(1);                                             \
    _Pragma("unroll") for (int kk = 0; kk < 2; ++kk)                           \
    _Pragma("unroll") for (int m = 0; m < 4; ++m)                              \
    _Pragma("unroll") for (int n = 0; n < 4; ++n)                              \
      ACC[m][n] = __builtin_amdgcn_mfma_f32_16x16x32_bf16(af[m][kk], bfr[n][kk],\
                                                          ACC[m][n], 0, 0, 0); \
    __builtin_amdgcn_s_setprio(0);                                             \
  } while (0)

  // prologue: items 0 (H tile0 -> buf0) and 1 (L tile0 -> buf1)
  ST(0, AH, 0);
  {
    const unsigned short* P; unsigned kf;
    ITEM(1, P, kf);
    ST(1, P, kf);
  }

  // interleaved region: steps 2t (H tile t, buf0), 2t+1 (L tile t, buf1)
  for (int t = 0; t < nkL; ++t) {
    PVSTEP(0, accH, 2 * t + 2);
    PVSTEP(1, accL, 2 * t + 3);
  }
  // solo region: H tiles nkL..nkH-1 in buffer-alternating pairs (count even)
  for (int u = nkL; u < nkH; u += 2) {
    PVSTEP(0, accH, u + nkL + 2);
    PVSTEP(1, accH, u + nkL + 3);
  }
#undef PVSTEP

  const int cr = l4 * 4;
#pragma unroll
  for (int n = 0; n < 4; ++n) {
    int col = bx * 128 + wc + n * 16 + l15;
#pragma unroll
    for (int m = 0; m < 4; ++m) {
      int rH = byH * 128 + wr + m * 16 + cr;
      int rL = p * 128 + wr + m * 16 + cr;
#pragma unroll
      for (int i = 0; i < 4; ++i) {
        Ob[(size_t)(rH + i) * 1024 + col] = accH[m][n][i];
        Ob[(size_t)(rL + i) * 1024 + col] = accL[m][n][i];
      }
    }
  }
}

// ---------------- causal softmax over S rows (in place, bf16) ----------------
// Loads cols < nv; stores cols < bound = ceil128(t+1) — exactly the K-range
// gemm_pv2's 128-tile truncation reads (zero-fills masked remainder).
__global__ __launch_bounds__(256) void softmax_causal(unsigned short* __restrict__ S) {
  const int T = 2048;
  int t = blockIdx.x, b = blockIdx.y;
  unsigned short* row = S + ((size_t)b * T + t) * T;
  const int nv = t + 1;
  const int bound = ((t >> 7) + 1) << 7;
  int tid = threadIdx.x;
  int lane = tid & 63, wid = tid >> 6;
  int s0 = tid * 8;
  us8 raw = {};
  if (s0 < nv) raw = *(const us8*)(row + s0);
  float v[8];
  float m = -3.0e38f;
#pragma unroll
  for (int j = 0; j < 8; ++j) {
    v[j] = bf2f(raw[j]);
    if (s0 + j < nv) m = fmaxf(m, v[j]);
  }
#pragma unroll
  for (int o = 32; o > 0; o >>= 1) m = fmaxf(m, __shfl_xor(m, o, 64));
  __shared__ float red[4];
  if (lane == 0) red[wid] = m;
  __syncthreads();
  m = fmaxf(fmaxf(red[0], red[1]), fmaxf(red[2], red[3]));
  __syncthreads();
  float sum = 0.f;
#pragma unroll
  for (int j = 0; j < 8; ++j) {
    float e = (s0 + j < nv) ? exp2f(v[j] - m) : 0.f;
    v[j] = e;
    sum += e;
  }
#pragma unroll
  for (int o = 32; o > 0; o >>= 1) sum += __shfl_xor(sum, o, 64);
  if (lane == 0) red[wid] = sum;
  __syncthreads();
  sum = red[0] + red[1] + red[2] + red[3];
  float inv = 1.0f / sum;
  if (s0 < bound) {
    us8 outv;
#pragma unroll
    for (int j = 0; j < 8; ++j) outv[j] = f2bf(v[j] * inv);
    *(us8*)(row + s0) = outv;
  }
}

extern "C" void kernel_launch(void* const* d_in, const int* in_sizes, int n_in,
                              void* d_out, int out_size, void* d_ws, size_t ws_size,
                              hipStream_t stream) {
  const float* x = (const float*)d_in[0];      // [4,2048,1024]
  const float* W = (const float*)d_in[1];      // [3072,1024]
  const float* bias = (const float*)d_in[2];   // [3072]
  float* out = (float*)d_out;                  // [4,2048,1024]

  char* ws = (char*)d_ws;
  if (ws_size < 106954752u) return;
  unsigned short* xbf = (unsigned short*)(ws);
  unsigned short* vT = xbf;  // alias: xbf dead after gemm_g0
  unsigned short* wbf = (unsigned short*)(ws + 16777216);
  unsigned short* kqv = (unsigned short*)(ws + 23068672);
  unsigned short* S = (unsigned short*)(ws + 73400320);

  const float kSoftmaxScale = 1.4426950408889634f / 32.0f;  // log2(e)/sqrt(1024)

  cvt_bf16_2<<<11264, 256, 0, stream>>>(x, xbf, 2097152, W, wbf, 786432);

  // kqv = x @ W^T + b : 128x384 tiles, 8x64 = 512 blocks = 2 exact rounds
  gemm_g0<<<dim3(512, 1, 1), 512, 0, stream>>>(xbf, wbf, kqv, bias);

  transpose_v<<<dim3(32, 16, 4), 256, 0, stream>>>(kqv, vT);

  // S = (k @ q^T) * log2e/32 (bf16), causal blocks skipped
  gemm_s<<<dim3(8, 8, 4), 512, 0, stream>>>(
      kqv, 3072, 2048LL * 3072, kqv + 1024, 3072, 2048LL * 3072,
      S, 2048, 2048LL * 2048, kSoftmaxScale, 1024);

  softmax_causal<<<dim3(2048, 4), 256, 0, stream>>>(S);

  // out = P @ vT^T (fp32): two-chain blocks, uniform 34 K-tiles, 256 = 1/CU
  gemm_pv2<<<dim3(256, 1, 1), 256, 0, stream>>>(S, vT, out);
}